// Round 7
// baseline (848.272 us; speedup 1.0000x reference)
//
#include <hip/hip_runtime.h>
#include <math.h>

#define N 256
#define Dd 128

__device__ __forceinline__ double inv2s2_of(int s){
    return (s==0)?0.5:(s==1)?5.0e-3:(s==2)?5.0e-5:5.0e-7;
}

// ---------------- gather: z1s = z1[perm1], z2s = z2[perm2] ----------------
__global__ void k_gather(const float* __restrict__ z1, const float* __restrict__ z2,
                         const int* __restrict__ p1, const int* __restrict__ p2,
                         float* __restrict__ z1s, float* __restrict__ z2s){
    int idx = blockIdx.x*256 + threadIdx.x;   // 0 .. 2*N*Dd-1
    int half = N*Dd;
    if (idx < half){
        int i = idx / Dd, t = idx % Dd;
        z1s[idx] = z1[p1[i]*Dd + t];
    } else {
        int j = idx - half;
        int i = j / Dd, t = j % Dd;
        z2s[j] = z2[p2[i]*Dd + t];
    }
}

// ------- fused distances + kernel matrices + bnum --------------------------
// w=0: (z1,z1)+(z2,z2)   -> Anum(f64,+lam) + S8[4..8)
// w=1: (z1,z1s)+(z2,z2s) -> bnum[s][row] += exp (shfl-reduced, f64 atomics)
// w=2: (z2s,z2s)         -> Aden(f64,+lam) + S8[0..4)
// w=3: (z2s,z2)          -> M4 (f32)
// w=4: (z1,z2)           -> U4 (f32)
__global__ void k_dist(const float* __restrict__ z1, const float* __restrict__ z2,
                       const float* __restrict__ z1s, const float* __restrict__ z2s,
                       double* __restrict__ Aden, double* __restrict__ Anum,
                       double* __restrict__ S8, float* __restrict__ M4,
                       float* __restrict__ U4, double* __restrict__ bnum){
    __shared__ float Xs[16][17], Ys[16][17];
    int w = blockIdx.z;
    const float *X1, *Y1, *X2, *Y2; int npair;
    switch(w){
        case 0: X1=z1;  Y1=z1;  X2=z2; Y2=z2;  npair=2; break;
        case 1: X1=z1;  Y1=z1s; X2=z2; Y2=z2s; npair=2; break;
        case 2: X1=z2s; Y1=z2s; X2=0;  Y2=0;   npair=1; break;
        case 3: X1=z2s; Y1=z2;  X2=0;  Y2=0;   npair=1; break;
        default:X1=z1;  Y1=z2;  X2=0;  Y2=0;   npair=1; break;
    }
    int tx = threadIdx.x, ty = threadIdx.y;
    int row = blockIdx.y*16 + ty, col = blockIdx.x*16 + tx;
    double acc = 0.0;
    for (int p = 0; p < npair; p++){
        const float* X = p ? X2 : X1;
        const float* Y = p ? Y2 : Y1;
        for (int c = 0; c < Dd; c += 16){
            __syncthreads();
            Xs[ty][tx] = X[(blockIdx.y*16+ty)*Dd + c + tx];
            Ys[ty][tx] = Y[(blockIdx.x*16+ty)*Dd + c + tx];
            __syncthreads();
            #pragma unroll
            for (int t = 0; t < 16; t++){
                float d = Xs[ty][t] - Ys[tx][t];
                acc += (double)d * (double)d;
            }
        }
    }
    int o = row*N + col;
    if (w == 0){
        #pragma unroll
        for (int s = 0; s < 4; s++){
            double v = exp(-inv2s2_of(s)*acc);
            if (row == col) v += 1.0e-3;
            Anum[s*N*N + o] = v;
            S8[(4+s)*N*N + o] = v;
        }
    } else if (w == 1){
        #pragma unroll
        for (int s = 0; s < 4; s++){
            double v = exp(-inv2s2_of(s)*acc);
            v += __shfl_down(v, 8, 16);
            v += __shfl_down(v, 4, 16);
            v += __shfl_down(v, 2, 16);
            v += __shfl_down(v, 1, 16);
            if (tx == 0) atomicAdd(&bnum[s*N + row], v);
        }
    } else if (w == 2){
        #pragma unroll
        for (int s = 0; s < 4; s++){
            double v = exp(-inv2s2_of(s)*acc);
            if (row == col) v += 1.0e-3;
            Aden[s*N*N + o] = v;
            S8[s*N*N + o] = v;
        }
    } else if (w == 3){
        #pragma unroll
        for (int s = 0; s < 4; s++) M4[s*N*N + o] = (float)exp(-inv2s2_of(s)*acc);
    } else {
        #pragma unroll
        for (int s = 0; s < 4; s++) U4[s*N*N + o] = (float)exp(-inv2s2_of(s)*acc);
    }
}

// ================= fused blocked f64 Gauss-Jordan inversion =================
// ONE launch, 64 blocks x 1024 thr (mat = bid>>3, part = bid&7), hand-rolled
// device-scope grid barrier (64 blocks <= CU count, 16 waves + 34KB LDS per
// block => all co-resident). Same verified f64 algebra as rounds 4-6.
__device__ __forceinline__ void gbar(unsigned* cnt, unsigned* gen, unsigned nb){
    __syncthreads();
    if (threadIdx.x == 0){
        __threadfence();
        unsigned g = __hip_atomic_load(gen, __ATOMIC_RELAXED, __HIP_MEMORY_SCOPE_AGENT);
        unsigned a = __hip_atomic_fetch_add(cnt, 1u, __ATOMIC_ACQ_REL, __HIP_MEMORY_SCOPE_AGENT);
        if (a == nb - 1u){
            __hip_atomic_store(cnt, 0u, __ATOMIC_RELAXED, __HIP_MEMORY_SCOPE_AGENT);
            __hip_atomic_fetch_add(gen, 1u, __ATOMIC_ACQ_REL, __HIP_MEMORY_SCOPE_AGENT);
        } else {
            while (__hip_atomic_load(gen, __ATOMIC_ACQUIRE, __HIP_MEMORY_SCOPE_AGENT) == g){}
        }
        __threadfence();
    }
    __syncthreads();
}

__launch_bounds__(1024, 1)
__global__ void k_inv(double* __restrict__ S8, double* __restrict__ Eg,
                      double* __restrict__ Pg, unsigned* __restrict__ bar,
                      float* __restrict__ Gden, float* __restrict__ Gnum){
    __shared__ double Pl[32][33], EJ[32][33], El[32][33], Cl[32][33];
    int bid = blockIdx.x;
    int mat = bid >> 3, part = bid & 7;
    double* S = S8 + (size_t)mat*65536;
    double* E = Eg + (size_t)mat*7168;
    double* Pp = Pg + (size_t)mat*1024;
    int tid = threadIdx.x;
    unsigned* cnt = bar; unsigned* gen = bar + 1;

    for (int k = 0; k < 8; k++){
        int Kb = k*32;
        // ---- phase A: snapshot E slice (all blocks); part 0 sweeps pivot ----
        for (int t = tid; t < 896; t += 1024){
            int e = part*896 + t;
            int ri = e >> 5, kk = e & 31;
            int gi = (ri < Kb) ? ri : ri + 32;
            E[e] = S[(size_t)gi*N + Kb + kk];
        }
        if (part == 0){
            int i = tid >> 5, j = tid & 31;
            Pl[i][j] = S[(size_t)(Kb+i)*N + Kb + j];
            __syncthreads();
            if (tid < 64){
                int r = tid & 31, cg = tid >> 5;
                for (int j2 = 0; j2 < 32; j2++){
                    double d    = Pl[j2][j2];
                    double invd = 1.0 / d;
                    double cr   = Pl[r][j2];
                    double s    = cr * invd;
                    bool rj = (r == j2);
                    double nv[16];
                    #pragma unroll
                    for (int c = 0; c < 16; c++){
                        int col = cg*16 + c;
                        double pj = Pl[j2][col];
                        double v  = Pl[r][col];
                        nv[c] = rj ? ((col == j2) ? -invd : v * invd)
                                   : ((col == j2) ? s : v - s*pj);
                    }
                    #pragma unroll
                    for (int c = 0; c < 16; c++) Pl[r][cg*16+c] = nv[c];
                }
                #pragma unroll
                for (int c = 0; c < 16; c++) Pl[r][cg*16+c] = -Pl[r][cg*16+c];
            }
            __syncthreads();
            Pp[tid] = Pl[i][j];
            S[(size_t)(Kb+i)*N + Kb + j] = -Pl[i][j];
        }
        gbar(cnt, gen, 64);
        // ---- phase B: 7 tile tasks per block ----
        for (int tt = 0; tt < 7; tt++){
            int t = part*7 + tt;
            int r = tid >> 5, c = tid & 31;     // 1024 covers 32x32
            Pl[r][c] = Pp[tid];
            if (t < 49){
                int I = t / 7, J = t % 7;
                EJ[r][c] = E[(J*32 + r)*32 + c];
                El[r][c] = E[(I*32 + r)*32 + c];
                __syncthreads();
                double acc = 0.0;
                #pragma unroll
                for (int kk = 0; kk < 32; kk++) acc += EJ[r][kk] * Pl[kk][c];
                Cl[r][c] = acc;
                __syncthreads();
                double acc2 = 0.0;
                #pragma unroll
                for (int kk = 0; kk < 32; kk++) acc2 += El[r][kk] * Cl[c][kk];
                int gI = (I*32 < Kb) ? I*32 : I*32 + 32;
                int gJ = (J*32 < Kb) ? J*32 : J*32 + 32;
                S[(size_t)(gI + r)*N + gJ + c] -= acc2;
            } else {
                int T = t - 49;
                El[r][c] = E[(T*32 + r)*32 + c];
                __syncthreads();
                double acc = 0.0;
                #pragma unroll
                for (int kk = 0; kk < 32; kk++) acc += El[r][kk] * Pl[kk][c];
                Cl[r][c] = acc;
                __syncthreads();
                int gT = (T*32 < Kb) ? T*32 : T*32 + 32;
                S[(size_t)(gT + r)*N + Kb + c] = Cl[r][c];       // col block
                S[(size_t)(Kb + r)*N + gT + c] = Cl[c][r];       // row block = C^T
            }
            __syncthreads();
        }
        gbar(cnt, gen, 64);
    }
    // ---- writeout G = -(swept), cast f32 ----
    for (int e = tid; e < 8192; e += 1024){
        int idx = bid*8192 + e;
        int m = idx >> 16, off = idx & 65535;
        float g = -(float)S8[idx];
        if (m < 4) Gden[m*65536 + off] = g;
        else       Gnum[(m-4)*65536 + off] = g;
    }
}

// ---------------- B = M * U^T (f32 in, f64 accum/out), batched over sigma --------
__global__ void k_gemm_nt(const float* __restrict__ M4, const float* __restrict__ U4,
                          double* __restrict__ Bmat){
    int s = blockIdx.z;
    const float* Mp = M4 + s*N*N;
    const float* Up = U4 + s*N*N;
    double* Bp = Bmat + s*N*N;
    __shared__ float Ms[32][33], Us[32][33];
    int tx = threadIdx.x, ty = threadIdx.y;
    int tid = ty*16 + tx;
    int bj = blockIdx.y*32, bi = blockIdx.x*32;
    double a00=0, a01=0, a10=0, a11=0;
    for (int kc = 0; kc < N; kc += 32){
        __syncthreads();
        #pragma unroll
        for (int l = 0; l < 4; l++){
            int e = tid + l*256; int r = e >> 5, c = e & 31;
            Ms[r][c] = Mp[(bj+r)*N + kc + c];
            Us[r][c] = Up[(bi+r)*N + kc + c];
        }
        __syncthreads();
        #pragma unroll
        for (int k = 0; k < 32; k++){
            float x0 = Ms[2*ty][k], x1 = Ms[2*ty+1][k];
            float y0 = Us[2*tx][k], y1 = Us[2*tx+1][k];
            a00 += (double)x0*y0; a01 += (double)x0*y1;
            a10 += (double)x1*y0; a11 += (double)x1*y1;
        }
    }
    Bp[(bj+2*ty  )*N + bi+2*tx  ] = a00;
    Bp[(bj+2*ty  )*N + bi+2*tx+1] = a01;
    Bp[(bj+2*ty+1)*N + bi+2*tx  ] = a10;
    Bp[(bj+2*ty+1)*N + bi+2*tx+1] = a11;
}

// ---------------- X0 = G * B  (G f32, B f64 -> X0 f32, f64 accum) ----------------
__global__ void k_gemm_x0(const float* __restrict__ Gden, const double* __restrict__ Bmat,
                          float* __restrict__ X0){
    int s = blockIdx.z;
    const float* Gp = Gden + s*N*N;
    const double* Bp = Bmat + s*N*N;
    float* Xp = X0 + s*N*N;
    __shared__ float Gs[32][33];
    __shared__ double Bs[32][33];
    int tx = threadIdx.x, ty = threadIdx.y;
    int tid = ty*16 + tx;
    int bj = blockIdx.y*32, bi = blockIdx.x*32;
    double a00=0, a01=0, a10=0, a11=0;
    for (int kc = 0; kc < N; kc += 32){
        __syncthreads();
        #pragma unroll
        for (int l = 0; l < 4; l++){
            int e = tid + l*256; int r = e >> 5, c = e & 31;
            Gs[r][c] = Gp[(bj+r)*N + kc + c];
            Bs[r][c] = Bp[(kc+r)*N + bi + c];
        }
        __syncthreads();
        #pragma unroll
        for (int k = 0; k < 32; k++){
            float x0 = Gs[2*ty][k], x1 = Gs[2*ty+1][k];
            double y0 = Bs[k][2*tx], y1 = Bs[k][2*tx+1];
            a00 += (double)x0*y0; a01 += (double)x0*y1;
            a10 += (double)x1*y0; a11 += (double)x1*y1;
        }
    }
    Xp[(bj+2*ty  )*N + bi+2*tx  ] = (float)a00;
    Xp[(bj+2*ty  )*N + bi+2*tx+1] = (float)a01;
    Xp[(bj+2*ty+1)*N + bi+2*tx  ] = (float)a10;
    Xp[(bj+2*ty+1)*N + bi+2*tx+1] = (float)a11;
}

// ---------------- R = B - A * X0  (A f64, X0 f32 -> R f32, f64 accum) ------------
__global__ void k_gemm_r(const double* __restrict__ Aden, const float* __restrict__ X0,
                         const double* __restrict__ Bmat, float* __restrict__ Rm){
    int s = blockIdx.z;
    const double* Ap = Aden + s*N*N;
    const float* Xp = X0 + s*N*N;
    const double* Bp = Bmat + s*N*N;
    float* Rp = Rm + s*N*N;
    __shared__ double As[32][33];
    __shared__ float Xs[32][33];
    int tx = threadIdx.x, ty = threadIdx.y;
    int tid = ty*16 + tx;
    int bj = blockIdx.y*32, bi = blockIdx.x*32;
    double a00=0, a01=0, a10=0, a11=0;
    for (int kc = 0; kc < N; kc += 32){
        __syncthreads();
        #pragma unroll
        for (int l = 0; l < 4; l++){
            int e = tid + l*256; int r = e >> 5, c = e & 31;
            As[r][c] = Ap[(bj+r)*N + kc + c];
            Xs[r][c] = Xp[(kc+r)*N + bi + c];
        }
        __syncthreads();
        #pragma unroll
        for (int k = 0; k < 32; k++){
            double x0 = As[2*ty][k], x1 = As[2*ty+1][k];
            double y0 = (double)Xs[k][2*tx], y1 = (double)Xs[k][2*tx+1];
            a00 += x0*y0; a01 += x0*y1;
            a10 += x1*y0; a11 += x1*y1;
        }
    }
    int r0 = bj+2*ty, c0 = bi+2*tx;
    Rp[(r0  )*N + c0  ] = (float)(Bp[(r0  )*N + c0  ] - a00);
    Rp[(r0  )*N + c0+1] = (float)(Bp[(r0  )*N + c0+1] - a01);
    Rp[(r0+1)*N + c0  ] = (float)(Bp[(r0+1)*N + c0  ] - a10);
    Rp[(r0+1)*N + c0+1] = (float)(Bp[(r0+1)*N + c0+1] - a11);
}

// ------ X = X0 + G*R, looped over sigma; relu(avg) column sums -> dsum -------
__global__ void k_gemm_xl(const float* __restrict__ Gden, const float* __restrict__ Rm,
                          const float* __restrict__ X0, double* __restrict__ dsum){
    __shared__ float Gs[32][33], Rs[32][33];
    __shared__ double cp[16][33];
    int tx = threadIdx.x, ty = threadIdx.y;
    int tid = ty*16 + tx;
    int bj = blockIdx.y*32, bi = blockIdx.x*32;
    int r0 = bj+2*ty, c0 = bi+2*tx;
    double s00=0, s01=0, s10=0, s11=0;
    for (int s = 0; s < 4; s++){
        const float* Gp = Gden + s*N*N;
        const float* Rp = Rm + s*N*N;
        const float* X0p = X0 + s*N*N;
        double a00=0, a01=0, a10=0, a11=0;
        for (int kc = 0; kc < N; kc += 32){
            __syncthreads();
            #pragma unroll
            for (int l = 0; l < 4; l++){
                int e = tid + l*256; int r = e >> 5, c = e & 31;
                Gs[r][c] = Gp[(bj+r)*N + kc + c];
                Rs[r][c] = Rp[(kc+r)*N + bi + c];
            }
            __syncthreads();
            #pragma unroll
            for (int k = 0; k < 32; k++){
                float x0 = Gs[2*ty][k], x1 = Gs[2*ty+1][k];
                float y0 = Rs[k][2*tx], y1 = Rs[k][2*tx+1];
                a00 += (double)x0*y0; a01 += (double)x0*y1;
                a10 += (double)x1*y0; a11 += (double)x1*y1;
            }
        }
        s00 += (double)X0p[(r0  )*N + c0  ] + a00;
        s01 += (double)X0p[(r0  )*N + c0+1] + a01;
        s10 += (double)X0p[(r0+1)*N + c0  ] + a10;
        s11 += (double)X0p[(r0+1)*N + c0+1] + a11;
    }
    // relu of sigma-average (match float pipeline: cast to f32 first)
    double v00 = (double)fmaxf((float)(0.25*s00), 0.f);
    double v01 = (double)fmaxf((float)(0.25*s01), 0.f);
    double v10 = (double)fmaxf((float)(0.25*s10), 0.f);
    double v11 = (double)fmaxf((float)(0.25*s11), 0.f);
    __syncthreads();
    cp[ty][2*tx]   = v00 + v10;
    cp[ty][2*tx+1] = v01 + v11;
    __syncthreads();
    if (tid < 32){
        double ssum = 0;
        #pragma unroll
        for (int t = 0; t < 16; t++) ssum += cp[t][tid];
        atomicAdd(&dsum[bi + tid], ssum);
    }
}

// ---------------- numerator solves: y = Gnum*b, + one IR step ----------------
__global__ void k_numsolve(const float* __restrict__ Gnum, const double* __restrict__ Anum,
                           const double* __restrict__ bnum, float* __restrict__ rnum){
    __shared__ double y0[256], rr[256], bsh[256];
    int s = blockIdx.x, j = threadIdx.x;
    const float* Gp = Gnum + s*N*N;
    const double* Ap = Anum + s*N*N;
    const double* bp = bnum + s*N;
    bsh[j] = bp[j];
    __syncthreads();
    double acc = 0;
    for (int k = 0; k < N; k++) acc += (double)Gp[j*N+k] * bsh[k];
    y0[j] = acc;
    __syncthreads();
    acc = 0;
    for (int k = 0; k < N; k++) acc += Ap[j*N+k] * y0[k];
    rr[j] = bsh[j] - acc;
    __syncthreads();
    acc = 0;
    for (int k = 0; k < N; k++) acc += (double)Gp[j*N+k] * rr[k];
    rnum[s*N+j] = (float)(y0[j] + acc);
}

// ---------------- final loss ----------------
__global__ void k_loss2(const double* __restrict__ dsum, const float* __restrict__ rnum,
                        float* __restrict__ out){
    __shared__ double red[256];
    int i = threadIdx.x;
    double denum = dsum[i] + (double)N * 1.0e-3;
    float ravg = 0.25f*(rnum[0*N+i] + rnum[1*N+i] + rnum[2*N+i] + rnum[3*N+i]);
    double rn = (double)fmaxf(ravg, 0.f) + 1.0e-3;
    red[i] = log(rn) + log(denum);
    __syncthreads();
    for (int st = 128; st > 0; st >>= 1){
        if (i < st) red[i] += red[i + st];
        __syncthreads();
    }
    if (i == 0) out[0] = (float)red[0];
}

extern "C" void kernel_launch(void* const* d_in, const int* in_sizes, int n_in,
                              void* d_out, int out_size, void* d_ws, size_t ws_size,
                              hipStream_t stream) {
    (void)in_sizes; (void)n_in; (void)out_size; (void)ws_size;
    const float* z1 = (const float*)d_in[0];
    const float* z2 = (const float*)d_in[1];
    const int*   p1 = (const int*)d_in[2];
    const int*   p2 = (const int*)d_in[3];
    float* out = (float*)d_out;

    char* w = (char*)d_ws;
    size_t o = 0;
    auto carve = [&](size_t bytes) -> char* {
        char* p = w + o;
        o += (bytes + 255) & ~(size_t)255;
        return p;
    };
    // zero-init region first (one memset covers bar+bnum+dsum)
    unsigned* bar  = (unsigned*)carve(256);
    double*   bnum = (double*) carve((size_t)4*N*sizeof(double));
    double*   dsum = (double*) carve((size_t)N*sizeof(double));
    size_t zbytes = o;
    float*  z1s  = (float*) carve(N*Dd*sizeof(float));
    float*  z2s  = (float*) carve(N*Dd*sizeof(float));
    double* Aden = (double*)carve((size_t)4*N*N*sizeof(double));
    double* Anum = (double*)carve((size_t)4*N*N*sizeof(double));
    float*  M4   = (float*) carve((size_t)4*N*N*sizeof(float));
    float*  U4   = (float*) carve((size_t)4*N*N*sizeof(float));
    double* Bmat = (double*)carve((size_t)4*N*N*sizeof(double));
    float*  Gden = (float*) carve((size_t)4*N*N*sizeof(float));
    float*  Gnum = (float*) carve((size_t)4*N*N*sizeof(float));
    float*  X0   = (float*) carve((size_t)4*N*N*sizeof(float));
    float*  Rm   = (float*) carve((size_t)4*N*N*sizeof(float));
    float*  rnum = (float*) carve((size_t)4*N*sizeof(float));
    double* Smat = (double*)carve((size_t)8*N*N*sizeof(double));
    double* Eg   = (double*)carve((size_t)8*224*32*sizeof(double));
    double* Pg   = (double*)carve((size_t)8*32*32*sizeof(double));

    hipMemsetAsync(d_ws, 0, zbytes, stream);
    k_gather<<<dim3((2*N*Dd)/256), dim3(256), 0, stream>>>(z1, z2, p1, p2, z1s, z2s);
    k_dist<<<dim3(16,16,5), dim3(16,16), 0, stream>>>(z1, z2, z1s, z2s,
                                                      Aden, Anum, Smat, M4, U4, bnum);
    k_inv<<<dim3(64), dim3(1024), 0, stream>>>(Smat, Eg, Pg, bar, Gden, Gnum);
    k_gemm_nt<<<dim3(8,8,4), dim3(16,16), 0, stream>>>(M4, U4, Bmat);
    k_gemm_x0<<<dim3(8,8,4), dim3(16,16), 0, stream>>>(Gden, Bmat, X0);
    k_gemm_r<<<dim3(8,8,4), dim3(16,16), 0, stream>>>(Aden, X0, Bmat, Rm);
    k_gemm_xl<<<dim3(8,8), dim3(16,16), 0, stream>>>(Gden, Rm, X0, dsum);
    k_numsolve<<<dim3(4), dim3(256), 0, stream>>>(Gnum, Anum, bnum, rnum);
    k_loss2<<<dim3(1), dim3(256), 0, stream>>>(dsum, rnum, out);
}

// Round 8
// 796.582 us; speedup vs baseline: 1.0649x; 1.0649x over previous
//
#include <hip/hip_runtime.h>
#include <math.h>

#define N 256
#define Dd 128
#define NBLK 64

__device__ __forceinline__ double inv2s2_of(int s){
    return (s==0)?0.5:(s==1)?5.0e-3:(s==2)?5.0e-5:5.0e-7;
}

// ------- fused gather + distances + kernel matrices + bnum ------------------
// w=0: (z1,z1)+(z2,z2)     -> Anum(f64,+lam) + S8[4..8)
// w=1: (z1,z1[p1])+(z2,z2[p2]) -> bnum[s][row] += exp (shfl-reduced, f64 atomics)
// w=2: (z2[p2],z2[p2])     -> Aden(f64,+lam) + S8[0..4)
// w=3: (z2[p2],z2)         -> M4 (f32)
// w=4: (z1,z2)             -> U4 (f32)
__global__ void k_dist(const float* __restrict__ z1, const float* __restrict__ z2,
                       const int* __restrict__ p1, const int* __restrict__ p2,
                       double* __restrict__ Aden, double* __restrict__ Anum,
                       double* __restrict__ S8, float* __restrict__ M4,
                       float* __restrict__ U4, double* __restrict__ bnum){
    __shared__ float Xs[16][17], Ys[16][17];
    int w = blockIdx.z;
    int tx = threadIdx.x, ty = threadIdx.y;
    int row = blockIdx.y*16 + ty, col = blockIdx.x*16 + tx;
    const float *Xb[2], *Yb[2]; const int *Xp[2], *Yp[2]; int npair = 1;
    Xb[1]=0; Yb[1]=0; Xp[0]=0; Yp[0]=0; Xp[1]=0; Yp[1]=0;
    switch(w){
        case 0: Xb[0]=z1; Yb[0]=z1; Xb[1]=z2; Yb[1]=z2; npair=2; break;
        case 1: Xb[0]=z1; Yb[0]=z1; Yp[0]=p1; Xb[1]=z2; Yb[1]=z2; Yp[1]=p2; npair=2; break;
        case 2: Xb[0]=z2; Yb[0]=z2; Xp[0]=p2; Yp[0]=p2; break;
        case 3: Xb[0]=z2; Yb[0]=z2; Xp[0]=p2; break;
        default:Xb[0]=z1; Yb[0]=z2; break;
    }
    double acc = 0.0;
    for (int p = 0; p < npair; p++){
        const float* X = Xb[p]; const float* Y = Yb[p];
        int xr = blockIdx.y*16 + ty; if (Xp[p]) xr = Xp[p][xr];
        int yr = blockIdx.x*16 + ty; if (Yp[p]) yr = Yp[p][yr];
        for (int c = 0; c < Dd; c += 16){
            __syncthreads();
            Xs[ty][tx] = X[xr*Dd + c + tx];
            Ys[ty][tx] = Y[yr*Dd + c + tx];
            __syncthreads();
            #pragma unroll
            for (int t = 0; t < 16; t++){
                float d = Xs[ty][t] - Ys[tx][t];
                acc += (double)d * (double)d;
            }
        }
    }
    int o = row*N + col;
    if (w == 0){
        #pragma unroll
        for (int s = 0; s < 4; s++){
            double v = exp(-inv2s2_of(s)*acc);
            if (row == col) v += 1.0e-3;
            Anum[s*N*N + o] = v;
            S8[(4+s)*N*N + o] = v;
        }
    } else if (w == 1){
        #pragma unroll
        for (int s = 0; s < 4; s++){
            double v = exp(-inv2s2_of(s)*acc);
            v += __shfl_down(v, 8, 16);
            v += __shfl_down(v, 4, 16);
            v += __shfl_down(v, 2, 16);
            v += __shfl_down(v, 1, 16);
            if (tx == 0) atomicAdd(&bnum[s*N + row], v);
        }
    } else if (w == 2){
        #pragma unroll
        for (int s = 0; s < 4; s++){
            double v = exp(-inv2s2_of(s)*acc);
            if (row == col) v += 1.0e-3;
            Aden[s*N*N + o] = v;
            S8[s*N*N + o] = v;
        }
    } else if (w == 3){
        #pragma unroll
        for (int s = 0; s < 4; s++) M4[s*N*N + o] = (float)exp(-inv2s2_of(s)*acc);
    } else {
        #pragma unroll
        for (int s = 0; s < 4; s++) U4[s*N*N + o] = (float)exp(-inv2s2_of(s)*acc);
    }
}

// ================= fused blocked f64 Gauss-Jordan inversion =================
// Same verified algebra as round 7's k_inv; only the barrier and scheduling
// change. Two-level barrier: arrivals on one counter; 8 group leaders spin on
// global gen, 7 members/group spin on a per-group line; s_sleep backoff.
// bar layout (unsigned, 128B-spaced lines): cnt=bar[0], gen=bar[32],
// ggen[g]=bar[64+32g].
__device__ __forceinline__ void gbar2(unsigned* bar, int bid){
    __syncthreads();
    if (threadIdx.x == 0){
        int grp = bid >> 3;
        bool leader = (bid & 7) == 0;
        unsigned* cnt = bar;
        unsigned* gen = bar + 32;
        unsigned* gg  = bar + 64 + (grp << 5);
        unsigned g = __hip_atomic_load(gen, __ATOMIC_ACQUIRE, __HIP_MEMORY_SCOPE_AGENT);
        unsigned base = leader ? 0u
                       : __hip_atomic_load(gg, __ATOMIC_ACQUIRE, __HIP_MEMORY_SCOPE_AGENT);
        __threadfence();   // baseline reads + all prior writes complete before arrival
        unsigned a = __hip_atomic_fetch_add(cnt, 1u, __ATOMIC_ACQ_REL, __HIP_MEMORY_SCOPE_AGENT);
        if (a == NBLK - 1u){
            __hip_atomic_store(cnt, 0u, __ATOMIC_RELAXED, __HIP_MEMORY_SCOPE_AGENT);
            __hip_atomic_fetch_add(gen, 1u, __ATOMIC_ACQ_REL, __HIP_MEMORY_SCOPE_AGENT);
        }
        if (leader){
            while (__hip_atomic_load(gen, __ATOMIC_ACQUIRE, __HIP_MEMORY_SCOPE_AGENT) == g)
                __builtin_amdgcn_s_sleep(8);
            __hip_atomic_fetch_add(gg, 1u, __ATOMIC_ACQ_REL, __HIP_MEMORY_SCOPE_AGENT);
        } else {
            while (__hip_atomic_load(gg, __ATOMIC_ACQUIRE, __HIP_MEMORY_SCOPE_AGENT) == base)
                __builtin_amdgcn_s_sleep(8);
        }
        __threadfence();
    }
    __syncthreads();
}

__launch_bounds__(1024, 1)
__global__ void k_inv(double* __restrict__ S8, double* __restrict__ Eg,
                      double* __restrict__ Pg, unsigned* __restrict__ bar,
                      float* __restrict__ Gden, float* __restrict__ Gnum){
    __shared__ double Pl[32][33], El[32][33], EJ[32][33], Cl[32][33];
    int bid = blockIdx.x;
    int mat = bid >> 3, part = bid & 7;
    double* S = S8 + (size_t)mat*65536;
    double* E = Eg + (size_t)mat*7168;
    double* Pp = Pg + (size_t)mat*1024;
    int tid = threadIdx.x;

    for (int k = 0; k < 8; k++){
        int Kb = k*32;
        // ---- phase A: E-slice snapshot; part-0 blocks also sweep the pivot ----
        if (part == 0){
            if (tid < 64){
                int r = tid & 31, cg = tid >> 5;
                #pragma unroll
                for (int c = 0; c < 16; c++)
                    Pl[r][cg*16+c] = S[(size_t)(Kb+r)*N + Kb + cg*16+c];
                // wave-0 elementwise f64 sweep (round-1/4-verified formula)
                for (int j2 = 0; j2 < 32; j2++){
                    double d    = Pl[j2][j2];
                    double invd = 1.0 / d;
                    double cr   = Pl[r][j2];
                    double s    = cr * invd;
                    bool rj = (r == j2);
                    double nv[16];
                    #pragma unroll
                    for (int c = 0; c < 16; c++){
                        int col = cg*16 + c;
                        double pj = Pl[j2][col];
                        double v  = Pl[r][col];
                        nv[c] = rj ? ((col == j2) ? -invd : v * invd)
                                   : ((col == j2) ? s : v - s*pj);
                    }
                    #pragma unroll
                    for (int c = 0; c < 16; c++) Pl[r][cg*16+c] = nv[c];
                }
                #pragma unroll
                for (int c = 0; c < 16; c++) Pl[r][cg*16+c] = -Pl[r][cg*16+c];
            } else if (tid - 64 < 896){
                int e = tid - 64;               // part 0 slice
                int ri = e >> 5, kk = e & 31;
                int gi = (ri < Kb) ? ri : ri + 32;
                E[e] = S[(size_t)gi*N + Kb + kk];
            }
            __syncthreads();
            {
                int i = tid >> 5, j = tid & 31;
                Pp[tid] = Pl[i][j];
                S[(size_t)(Kb+i)*N + Kb + j] = -Pl[i][j];
            }
        } else {
            if (tid < 896){
                int e = part*896 + tid;
                int ri = e >> 5, kk = e & 31;
                int gi = (ri < Kb) ? ri : ri + 32;
                E[e] = S[(size_t)gi*N + Kb + kk];
            }
        }
        gbar2(bar, bid);
        // ---- phase B: 7 tile tasks per block ----
        {
            int r = tid >> 5, c = tid & 31;
            Pl[r][c] = Pp[tid];
            if (part < 7) El[r][c] = E[(part*32 + r)*32 + c];
        }
        __syncthreads();
        if (part < 7){
            int I = part;
            int gI = (I*32 < Kb) ? I*32 : I*32 + 32;
            for (int tt = 0; tt < 7; tt++){
                int r = tid >> 5, c = tid & 31;
                EJ[r][c] = E[(tt*32 + r)*32 + c];
                __syncthreads();
                double acc = 0.0;
                #pragma unroll
                for (int kk = 0; kk < 32; kk++) acc += EJ[r][kk] * Pl[kk][c];
                Cl[r][c] = acc;
                __syncthreads();
                double acc2 = 0.0;
                #pragma unroll
                for (int kk = 0; kk < 32; kk++) acc2 += El[r][kk] * Cl[c][kk];
                int gJ = (tt*32 < Kb) ? tt*32 : tt*32 + 32;
                S[(size_t)(gI + r)*N + gJ + c] -= acc2;
                __syncthreads();
            }
        } else {
            for (int tt = 0; tt < 7; tt++){
                int r = tid >> 5, c = tid & 31;
                EJ[r][c] = E[(tt*32 + r)*32 + c];
                __syncthreads();
                double acc = 0.0;
                #pragma unroll
                for (int kk = 0; kk < 32; kk++) acc += EJ[r][kk] * Pl[kk][c];
                Cl[r][c] = acc;
                __syncthreads();
                int gT = (tt*32 < Kb) ? tt*32 : tt*32 + 32;
                S[(size_t)(gT + r)*N + Kb + c] = Cl[r][c];   // col block
                S[(size_t)(Kb + r)*N + gT + c] = Cl[c][r];   // row block = C^T
                __syncthreads();
            }
        }
        gbar2(bar, bid);
    }
    // ---- writeout G = -(swept), cast f32 ----
    for (int e = tid; e < 8192; e += 1024){
        int idx = bid*8192 + e;
        int m = idx >> 16, off = idx & 65535;
        float g = -(float)S8[idx];
        if (m < 4) Gden[m*65536 + off] = g;
        else       Gnum[(m-4)*65536 + off] = g;
    }
}

// ---------------- B = M * U^T (f32 in, f64 accum/out), batched over sigma --------
__global__ void k_gemm_nt(const float* __restrict__ M4, const float* __restrict__ U4,
                          double* __restrict__ Bmat){
    int s = blockIdx.z;
    const float* Mp = M4 + s*N*N;
    const float* Up = U4 + s*N*N;
    double* Bp = Bmat + s*N*N;
    __shared__ float Ms[32][33], Us[32][33];
    int tx = threadIdx.x, ty = threadIdx.y;
    int tid = ty*16 + tx;
    int bj = blockIdx.y*32, bi = blockIdx.x*32;
    double a00=0, a01=0, a10=0, a11=0;
    for (int kc = 0; kc < N; kc += 32){
        __syncthreads();
        #pragma unroll
        for (int l = 0; l < 4; l++){
            int e = tid + l*256; int r = e >> 5, c = e & 31;
            Ms[r][c] = Mp[(bj+r)*N + kc + c];
            Us[r][c] = Up[(bi+r)*N + kc + c];
        }
        __syncthreads();
        #pragma unroll
        for (int k = 0; k < 32; k++){
            float x0 = Ms[2*ty][k], x1 = Ms[2*ty+1][k];
            float y0 = Us[2*tx][k], y1 = Us[2*tx+1][k];
            a00 += (double)x0*y0; a01 += (double)x0*y1;
            a10 += (double)x1*y0; a11 += (double)x1*y1;
        }
    }
    Bp[(bj+2*ty  )*N + bi+2*tx  ] = a00;
    Bp[(bj+2*ty  )*N + bi+2*tx+1] = a01;
    Bp[(bj+2*ty+1)*N + bi+2*tx  ] = a10;
    Bp[(bj+2*ty+1)*N + bi+2*tx+1] = a11;
}

// ---------------- X0 = G * B  (G f32, B f64 -> X0 f32, f64 accum) ----------------
__global__ void k_gemm_x0(const float* __restrict__ Gden, const double* __restrict__ Bmat,
                          float* __restrict__ X0){
    int s = blockIdx.z;
    const float* Gp = Gden + s*N*N;
    const double* Bp = Bmat + s*N*N;
    float* Xp = X0 + s*N*N;
    __shared__ float Gs[32][33];
    __shared__ double Bs[32][33];
    int tx = threadIdx.x, ty = threadIdx.y;
    int tid = ty*16 + tx;
    int bj = blockIdx.y*32, bi = blockIdx.x*32;
    double a00=0, a01=0, a10=0, a11=0;
    for (int kc = 0; kc < N; kc += 32){
        __syncthreads();
        #pragma unroll
        for (int l = 0; l < 4; l++){
            int e = tid + l*256; int r = e >> 5, c = e & 31;
            Gs[r][c] = Gp[(bj+r)*N + kc + c];
            Bs[r][c] = Bp[(kc+r)*N + bi + c];
        }
        __syncthreads();
        #pragma unroll
        for (int k = 0; k < 32; k++){
            float x0 = Gs[2*ty][k], x1 = Gs[2*ty+1][k];
            double y0 = Bs[k][2*tx], y1 = Bs[k][2*tx+1];
            a00 += (double)x0*y0; a01 += (double)x0*y1;
            a10 += (double)x1*y0; a11 += (double)x1*y1;
        }
    }
    Xp[(bj+2*ty  )*N + bi+2*tx  ] = (float)a00;
    Xp[(bj+2*ty  )*N + bi+2*tx+1] = (float)a01;
    Xp[(bj+2*ty+1)*N + bi+2*tx  ] = (float)a10;
    Xp[(bj+2*ty+1)*N + bi+2*tx+1] = (float)a11;
}

// ---------------- R = B - A * X0  (A f64, X0 f32 -> R f32, f64 accum) ------------
__global__ void k_gemm_r(const double* __restrict__ Aden, const float* __restrict__ X0,
                         const double* __restrict__ Bmat, float* __restrict__ Rm){
    int s = blockIdx.z;
    const double* Ap = Aden + s*N*N;
    const float* Xp = X0 + s*N*N;
    const double* Bp = Bmat + s*N*N;
    float* Rp = Rm + s*N*N;
    __shared__ double As[32][33];
    __shared__ float Xs[32][33];
    int tx = threadIdx.x, ty = threadIdx.y;
    int tid = ty*16 + tx;
    int bj = blockIdx.y*32, bi = blockIdx.x*32;
    double a00=0, a01=0, a10=0, a11=0;
    for (int kc = 0; kc < N; kc += 32){
        __syncthreads();
        #pragma unroll
        for (int l = 0; l < 4; l++){
            int e = tid + l*256; int r = e >> 5, c = e & 31;
            As[r][c] = Ap[(bj+r)*N + kc + c];
            Xs[r][c] = Xp[(kc+r)*N + bi + c];
        }
        __syncthreads();
        #pragma unroll
        for (int k = 0; k < 32; k++){
            double x0 = As[2*ty][k], x1 = As[2*ty+1][k];
            double y0 = (double)Xs[k][2*tx], y1 = (double)Xs[k][2*tx+1];
            a00 += x0*y0; a01 += x0*y1;
            a10 += x1*y0; a11 += x1*y1;
        }
    }
    int r0 = bj+2*ty, c0 = bi+2*tx;
    Rp[(r0  )*N + c0  ] = (float)(Bp[(r0  )*N + c0  ] - a00);
    Rp[(r0  )*N + c0+1] = (float)(Bp[(r0  )*N + c0+1] - a01);
    Rp[(r0+1)*N + c0  ] = (float)(Bp[(r0+1)*N + c0  ] - a10);
    Rp[(r0+1)*N + c0+1] = (float)(Bp[(r0+1)*N + c0+1] - a11);
}

// ---- X = X0 + G*R looped over sigma; relu(avg) col sums -> dsum.
// ---- Extra grid row (blockIdx.y==8, blockIdx.x<4): numerator solves -> rnum.
__global__ void k_gemm_xl(const float* __restrict__ Gden, const float* __restrict__ Rm,
                          const float* __restrict__ X0, double* __restrict__ dsum,
                          const float* __restrict__ Gnum, const double* __restrict__ Anum,
                          const double* __restrict__ bnum, float* __restrict__ rnum){
    __shared__ float Gs[32][33], Rs[32][33];
    __shared__ double cp[16][33];
    __shared__ double y0[256], rr2[256], bsh[256];
    int tx = threadIdx.x, ty = threadIdx.y;
    int tid = ty*16 + tx;
    if (blockIdx.y == 8){
        if (blockIdx.x >= 4) return;
        int s = blockIdx.x, j = tid;
        const float* Gp = Gnum + s*N*N;
        const double* Ap = Anum + s*N*N;
        const double* bp = bnum + s*N;
        bsh[j] = bp[j];
        __syncthreads();
        double acc = 0;
        for (int k = 0; k < N; k++) acc += (double)Gp[j*N+k] * bsh[k];
        y0[j] = acc;
        __syncthreads();
        acc = 0;
        for (int k = 0; k < N; k++) acc += Ap[j*N+k] * y0[k];
        rr2[j] = bsh[j] - acc;
        __syncthreads();
        acc = 0;
        for (int k = 0; k < N; k++) acc += (double)Gp[j*N+k] * rr2[k];
        rnum[s*N+j] = (float)(y0[j] + acc);
        return;
    }
    int bj = blockIdx.y*32, bi = blockIdx.x*32;
    int r0 = bj+2*ty, c0 = bi+2*tx;
    double s00=0, s01=0, s10=0, s11=0;
    for (int s = 0; s < 4; s++){
        const float* Gp = Gden + s*N*N;
        const float* Rp = Rm + s*N*N;
        const float* X0p = X0 + s*N*N;
        double a00=0, a01=0, a10=0, a11=0;
        for (int kc = 0; kc < N; kc += 32){
            __syncthreads();
            #pragma unroll
            for (int l = 0; l < 4; l++){
                int e = tid + l*256; int r = e >> 5, c = e & 31;
                Gs[r][c] = Gp[(bj+r)*N + kc + c];
                Rs[r][c] = Rp[(kc+r)*N + bi + c];
            }
            __syncthreads();
            #pragma unroll
            for (int k = 0; k < 32; k++){
                float x0 = Gs[2*ty][k], x1 = Gs[2*ty+1][k];
                float y0v = Rs[k][2*tx], y1v = Rs[k][2*tx+1];
                a00 += (double)x0*y0v; a01 += (double)x0*y1v;
                a10 += (double)x1*y0v; a11 += (double)x1*y1v;
            }
        }
        s00 += (double)X0p[(r0  )*N + c0  ] + a00;
        s01 += (double)X0p[(r0  )*N + c0+1] + a01;
        s10 += (double)X0p[(r0+1)*N + c0  ] + a10;
        s11 += (double)X0p[(r0+1)*N + c0+1] + a11;
    }
    double v00 = (double)fmaxf((float)(0.25*s00), 0.f);
    double v01 = (double)fmaxf((float)(0.25*s01), 0.f);
    double v10 = (double)fmaxf((float)(0.25*s10), 0.f);
    double v11 = (double)fmaxf((float)(0.25*s11), 0.f);
    __syncthreads();
    cp[ty][2*tx]   = v00 + v10;
    cp[ty][2*tx+1] = v01 + v11;
    __syncthreads();
    if (tid < 32){
        double ssum = 0;
        #pragma unroll
        for (int t = 0; t < 16; t++) ssum += cp[t][tid];
        atomicAdd(&dsum[bi + tid], ssum);
    }
}

// ---------------- final loss ----------------
__global__ void k_loss2(const double* __restrict__ dsum, const float* __restrict__ rnum,
                        float* __restrict__ out){
    __shared__ double red[256];
    int i = threadIdx.x;
    double denum = dsum[i] + (double)N * 1.0e-3;
    float ravg = 0.25f*(rnum[0*N+i] + rnum[1*N+i] + rnum[2*N+i] + rnum[3*N+i]);
    double rn = (double)fmaxf(ravg, 0.f) + 1.0e-3;
    red[i] = log(rn) + log(denum);
    __syncthreads();
    for (int st = 128; st > 0; st >>= 1){
        if (i < st) red[i] += red[i + st];
        __syncthreads();
    }
    if (i == 0) out[0] = (float)red[0];
}

extern "C" void kernel_launch(void* const* d_in, const int* in_sizes, int n_in,
                              void* d_out, int out_size, void* d_ws, size_t ws_size,
                              hipStream_t stream) {
    (void)in_sizes; (void)n_in; (void)out_size; (void)ws_size;
    const float* z1 = (const float*)d_in[0];
    const float* z2 = (const float*)d_in[1];
    const int*   p1 = (const int*)d_in[2];
    const int*   p2 = (const int*)d_in[3];
    float* out = (float*)d_out;

    char* w = (char*)d_ws;
    size_t o = 0;
    auto carve = [&](size_t bytes) -> char* {
        char* p = w + o;
        o += (bytes + 255) & ~(size_t)255;
        return p;
    };
    // zero-init region first (one memset covers bar+bnum+dsum)
    unsigned* bar  = (unsigned*)carve(2048);
    double*   bnum = (double*) carve((size_t)4*N*sizeof(double));
    double*   dsum = (double*) carve((size_t)N*sizeof(double));
    size_t zbytes = o;
    double* Aden = (double*)carve((size_t)4*N*N*sizeof(double));
    double* Anum = (double*)carve((size_t)4*N*N*sizeof(double));
    float*  M4   = (float*) carve((size_t)4*N*N*sizeof(float));
    float*  U4   = (float*) carve((size_t)4*N*N*sizeof(float));
    double* Bmat = (double*)carve((size_t)4*N*N*sizeof(double));
    float*  Gden = (float*) carve((size_t)4*N*N*sizeof(float));
    float*  Gnum = (float*) carve((size_t)4*N*N*sizeof(float));
    float*  X0   = (float*) carve((size_t)4*N*N*sizeof(float));
    float*  Rm   = (float*) carve((size_t)4*N*N*sizeof(float));
    float*  rnum = (float*) carve((size_t)4*N*sizeof(float));
    double* Smat = (double*)carve((size_t)8*N*N*sizeof(double));
    double* Eg   = (double*)carve((size_t)8*224*32*sizeof(double));
    double* Pg   = (double*)carve((size_t)8*32*32*sizeof(double));

    hipMemsetAsync(d_ws, 0, zbytes, stream);
    k_dist<<<dim3(16,16,5), dim3(16,16), 0, stream>>>(z1, z2, p1, p2,
                                                      Aden, Anum, Smat, M4, U4, bnum);
    k_inv<<<dim3(NBLK), dim3(1024), 0, stream>>>(Smat, Eg, Pg, bar, Gden, Gnum);
    k_gemm_nt<<<dim3(8,8,4), dim3(16,16), 0, stream>>>(M4, U4, Bmat);
    k_gemm_x0<<<dim3(8,8,4), dim3(16,16), 0, stream>>>(Gden, Bmat, X0);
    k_gemm_r<<<dim3(8,8,4), dim3(16,16), 0, stream>>>(Aden, X0, Bmat, Rm);
    k_gemm_xl<<<dim3(8,9), dim3(16,16), 0, stream>>>(Gden, Rm, X0, dsum,
                                                     Gnum, Anum, bnum, rnum);
    k_loss2<<<dim3(1), dim3(256), 0, stream>>>(dsum, rnum, out);
}

// Round 9
// 528.076 us; speedup vs baseline: 1.6063x; 1.5085x over previous
//
#include <hip/hip_runtime.h>
#include <math.h>

#define N 256
#define Dd 128

__device__ __forceinline__ double inv2s2_of(int s){
    return (s==0)?0.5:(s==1)?5.0e-3:(s==2)?5.0e-5:5.0e-7;
}

// ------- fused gather + distances + kernel matrices + bnum ------------------
// w=0: (z1,z1)+(z2,z2)         -> Anum(f64,+lam) + S8[4..8)
// w=1: (z1,z1[p1])+(z2,z2[p2]) -> bnum[s][row] += exp (shfl-reduced, f64 atomics)
// w=2: (z2[p2],z2[p2])         -> Aden(f64,+lam) + S8[0..4)
// w=3: (z2[p2],z2)             -> M4 (f32)
// w=4: (z1,z2)                 -> U4 (f32)
__global__ void k_dist(const float* __restrict__ z1, const float* __restrict__ z2,
                       const int* __restrict__ p1, const int* __restrict__ p2,
                       double* __restrict__ Aden, double* __restrict__ Anum,
                       double* __restrict__ S8, float* __restrict__ M4,
                       float* __restrict__ U4, double* __restrict__ bnum){
    __shared__ float Xs[16][17], Ys[16][17];
    int w = blockIdx.z;
    int tx = threadIdx.x, ty = threadIdx.y;
    int row = blockIdx.y*16 + ty, col = blockIdx.x*16 + tx;
    const float *Xb[2], *Yb[2]; const int *Xp[2], *Yp[2]; int npair = 1;
    Xb[1]=0; Yb[1]=0; Xp[0]=0; Yp[0]=0; Xp[1]=0; Yp[1]=0;
    switch(w){
        case 0: Xb[0]=z1; Yb[0]=z1; Xb[1]=z2; Yb[1]=z2; npair=2; break;
        case 1: Xb[0]=z1; Yb[0]=z1; Yp[0]=p1; Xb[1]=z2; Yb[1]=z2; Yp[1]=p2; npair=2; break;
        case 2: Xb[0]=z2; Yb[0]=z2; Xp[0]=p2; Yp[0]=p2; break;
        case 3: Xb[0]=z2; Yb[0]=z2; Xp[0]=p2; break;
        default:Xb[0]=z1; Yb[0]=z2; break;
    }
    double acc = 0.0;
    for (int p = 0; p < npair; p++){
        const float* X = Xb[p]; const float* Y = Yb[p];
        int xr = blockIdx.y*16 + ty; if (Xp[p]) xr = Xp[p][xr];
        int yr = blockIdx.x*16 + ty; if (Yp[p]) yr = Yp[p][yr];
        for (int c = 0; c < Dd; c += 16){
            __syncthreads();
            Xs[ty][tx] = X[xr*Dd + c + tx];
            Ys[ty][tx] = Y[yr*Dd + c + tx];
            __syncthreads();
            #pragma unroll
            for (int t = 0; t < 16; t++){
                float d = Xs[ty][t] - Ys[tx][t];
                acc += (double)d * (double)d;
            }
        }
    }
    int o = row*N + col;
    if (w == 0){
        #pragma unroll
        for (int s = 0; s < 4; s++){
            double v = exp(-inv2s2_of(s)*acc);
            if (row == col) v += 1.0e-3;
            Anum[s*N*N + o] = v;
            S8[(4+s)*N*N + o] = v;
        }
    } else if (w == 1){
        #pragma unroll
        for (int s = 0; s < 4; s++){
            double v = exp(-inv2s2_of(s)*acc);
            v += __shfl_down(v, 8, 16);
            v += __shfl_down(v, 4, 16);
            v += __shfl_down(v, 2, 16);
            v += __shfl_down(v, 1, 16);
            if (tx == 0) atomicAdd(&bnum[s*N + row], v);
        }
    } else if (w == 2){
        #pragma unroll
        for (int s = 0; s < 4; s++){
            double v = exp(-inv2s2_of(s)*acc);
            if (row == col) v += 1.0e-3;
            Aden[s*N*N + o] = v;
            S8[s*N*N + o] = v;
        }
    } else if (w == 3){
        #pragma unroll
        for (int s = 0; s < 4; s++) M4[s*N*N + o] = (float)exp(-inv2s2_of(s)*acc);
    } else {
        #pragma unroll
        for (int s = 0; s < 4; s++) U4[s*N*N + o] = (float)exp(-inv2s2_of(s)*acc);
    }
}

// ====== blocked f64 Gauss-Jordan inversion, multi-launch (round-6-verified) ======
// In-kernel grid barriers on gfx950 cost ~40us each (agent-scope acquire
// invalidates the per-XCD L2 -> 4MB refetch/step; rounds 7/8 measured 61MB,
// ~640us). Launch boundaries give XCD coherence for ~4us, so 16 small
// launches win.

// pivot: stage E panel -> Eg, stage+sweep pivot in LDS (wave 0, f64,
// round-1/4-verified formula), P -> Pg, -P -> S pivot block.
__launch_bounds__(1024, 1)
__global__ void k_pivot(double* __restrict__ S8, double* __restrict__ Eg,
                        double* __restrict__ Pg, int k){
    __shared__ double P[32][33];
    int mat = blockIdx.x;
    double* S = S8 + (size_t)mat*65536;
    double* E = Eg + (size_t)mat*7168;
    double* Pp = Pg + (size_t)mat*1024;
    int tid = threadIdx.x;
    int Kb = k*32;
    {
        int i = tid >> 5, j = tid & 31;   // 1024 covers 32x32
        P[i][j] = S[(size_t)(Kb+i)*N + Kb + j];
    }
    for (int e = tid; e < 7168; e += 1024){
        int ri = e >> 5, kk = e & 31;
        int gi = (ri < Kb) ? ri : ri + 32;
        E[e] = S[(size_t)gi*N + Kb + kk];
    }
    __syncthreads();
    if (tid < 64){
        int r = tid & 31, cg = tid >> 5;
        for (int j = 0; j < 32; j++){
            double d    = P[j][j];
            double invd = 1.0 / d;
            double cr   = P[r][j];
            double s    = cr * invd;
            bool rj = (r == j);
            double nv[16];
            #pragma unroll
            for (int c = 0; c < 16; c++){
                int col = cg*16 + c;
                double pj = P[j][col];
                double v  = P[r][col];
                nv[c] = rj ? ((col == j) ? -invd : v * invd)
                           : ((col == j) ? s : v - s*pj);
            }
            #pragma unroll
            for (int c = 0; c < 16; c++) P[r][cg*16+c] = nv[c];
        }
        #pragma unroll
        for (int c = 0; c < 16; c++) P[r][cg*16+c] = -P[r][cg*16+c];
    }
    __syncthreads();
    {
        int i = tid >> 5, j = tid & 31;
        Pp[tid] = P[i][j];
        S[(size_t)(Kb+i)*N + Kb + j] = -P[i][j];
    }
}

// step: blocks 0..48 trailing (I,J): C_J = E_J*P in LDS, F_IJ -= E_I * C_J^T.
//       blocks 49..55 colrow T: C_T = E_T*P, write col tile + row tile (C^T).
__launch_bounds__(256, 4)
__global__ void k_step(double* __restrict__ S8, const double* __restrict__ Eg,
                       const double* __restrict__ Pg, int k){
    __shared__ double Pl[32][33], EJ[32][33], Cl[32][33], El[32][33];
    int bx = blockIdx.x, mat = blockIdx.y;
    double* S = S8 + (size_t)mat*65536;
    const double* E = Eg + (size_t)mat*7168;
    const double* Pp = Pg + (size_t)mat*1024;
    int tid = threadIdx.x;
    int Kb = k*32;
    #pragma unroll
    for (int l = 0; l < 4; l++){
        int e = tid + l*256; int i = e >> 5, j = e & 31;
        Pl[i][j] = Pp[e];
    }
    if (bx < 49){
        int I = bx / 7, J = bx % 7;
        #pragma unroll
        for (int l = 0; l < 4; l++){
            int e = tid + l*256; int r = e >> 5, kk = e & 31;
            El[r][kk] = E[(I*32 + r)*32 + kk];
            EJ[r][kk] = E[(J*32 + r)*32 + kk];
        }
        __syncthreads();
        #pragma unroll
        for (int l = 0; l < 4; l++){
            int e = tid + l*256; int r = e >> 5, c = e & 31;
            double acc = 0.0;
            #pragma unroll
            for (int kk = 0; kk < 32; kk++) acc += EJ[r][kk] * Pl[kk][c];
            Cl[r][c] = acc;
        }
        __syncthreads();
        int pr = tid >> 4, pc = tid & 15;
        int r0 = 2*pr, c0 = 2*pc;
        double a00=0, a01=0, a10=0, a11=0;
        #pragma unroll
        for (int kk = 0; kk < 32; kk++){
            double e0 = El[r0][kk],   e1 = El[r0+1][kk];
            double b0 = Cl[c0][kk],   b1 = Cl[c0+1][kk];
            a00 += e0*b0; a01 += e0*b1;
            a10 += e1*b0; a11 += e1*b1;
        }
        int gI = (I*32 < Kb) ? I*32 : I*32 + 32;
        int gJ = (J*32 < Kb) ? J*32 : J*32 + 32;
        double* Sp = S + (size_t)(gI + r0)*N + gJ + c0;
        Sp[0]   -= a00; Sp[1]   -= a01;
        Sp[N]   -= a10; Sp[N+1] -= a11;
    } else {
        int T = bx - 49;
        #pragma unroll
        for (int l = 0; l < 4; l++){
            int e = tid + l*256; int r = e >> 5, kk = e & 31;
            El[r][kk] = E[(T*32 + r)*32 + kk];
        }
        __syncthreads();
        #pragma unroll
        for (int l = 0; l < 4; l++){
            int e = tid + l*256; int r = e >> 5, c = e & 31;
            double acc = 0.0;
            #pragma unroll
            for (int kk = 0; kk < 32; kk++) acc += El[r][kk] * Pl[kk][c];
            Cl[r][c] = acc;
        }
        __syncthreads();
        int gT = (T*32 < Kb) ? T*32 : T*32 + 32;
        #pragma unroll
        for (int l = 0; l < 4; l++){
            int e = tid + l*256; int r = e >> 5, c = e & 31;
            S[(size_t)(gT + r)*N + Kb + c] = Cl[r][c];
        }
        #pragma unroll
        for (int l = 0; l < 4; l++){
            int e = tid + l*256; int cc = e >> 5, rr = e & 31;
            S[(size_t)(Kb + cc)*N + gT + rr] = Cl[rr][cc];
        }
    }
}

// writeout: G = -(swept), cast f32
__global__ void k_gout(const double* __restrict__ S8,
                       float* __restrict__ Gden, float* __restrict__ Gnum){
    int idx = blockIdx.x*256 + threadIdx.x;
    int mat = idx >> 16, e = idx & 65535;
    float g = -(float)S8[idx];
    if (mat < 4) Gden[mat*65536 + e] = g;
    else         Gnum[(mat-4)*65536 + e] = g;
}

// ---------------- B = M * U^T (f32 in, f64 accum/out), batched over sigma --------
__global__ void k_gemm_nt(const float* __restrict__ M4, const float* __restrict__ U4,
                          double* __restrict__ Bmat){
    int s = blockIdx.z;
    const float* Mp = M4 + s*N*N;
    const float* Up = U4 + s*N*N;
    double* Bp = Bmat + s*N*N;
    __shared__ float Ms[32][33], Us[32][33];
    int tx = threadIdx.x, ty = threadIdx.y;
    int tid = ty*16 + tx;
    int bj = blockIdx.y*32, bi = blockIdx.x*32;
    double a00=0, a01=0, a10=0, a11=0;
    for (int kc = 0; kc < N; kc += 32){
        __syncthreads();
        #pragma unroll
        for (int l = 0; l < 4; l++){
            int e = tid + l*256; int r = e >> 5, c = e & 31;
            Ms[r][c] = Mp[(bj+r)*N + kc + c];
            Us[r][c] = Up[(bi+r)*N + kc + c];
        }
        __syncthreads();
        #pragma unroll
        for (int k = 0; k < 32; k++){
            float x0 = Ms[2*ty][k], x1 = Ms[2*ty+1][k];
            float y0 = Us[2*tx][k], y1 = Us[2*tx+1][k];
            a00 += (double)x0*y0; a01 += (double)x0*y1;
            a10 += (double)x1*y0; a11 += (double)x1*y1;
        }
    }
    Bp[(bj+2*ty  )*N + bi+2*tx  ] = a00;
    Bp[(bj+2*ty  )*N + bi+2*tx+1] = a01;
    Bp[(bj+2*ty+1)*N + bi+2*tx  ] = a10;
    Bp[(bj+2*ty+1)*N + bi+2*tx+1] = a11;
}

// ---------------- X0 = G * B  (G f32, B f64 -> X0 f32, f64 accum) ----------------
__global__ void k_gemm_x0(const float* __restrict__ Gden, const double* __restrict__ Bmat,
                          float* __restrict__ X0){
    int s = blockIdx.z;
    const float* Gp = Gden + s*N*N;
    const double* Bp = Bmat + s*N*N;
    float* Xp = X0 + s*N*N;
    __shared__ float Gs[32][33];
    __shared__ double Bs[32][33];
    int tx = threadIdx.x, ty = threadIdx.y;
    int tid = ty*16 + tx;
    int bj = blockIdx.y*32, bi = blockIdx.x*32;
    double a00=0, a01=0, a10=0, a11=0;
    for (int kc = 0; kc < N; kc += 32){
        __syncthreads();
        #pragma unroll
        for (int l = 0; l < 4; l++){
            int e = tid + l*256; int r = e >> 5, c = e & 31;
            Gs[r][c] = Gp[(bj+r)*N + kc + c];
            Bs[r][c] = Bp[(kc+r)*N + bi + c];
        }
        __syncthreads();
        #pragma unroll
        for (int k = 0; k < 32; k++){
            float x0 = Gs[2*ty][k], x1 = Gs[2*ty+1][k];
            double y0 = Bs[k][2*tx], y1 = Bs[k][2*tx+1];
            a00 += (double)x0*y0; a01 += (double)x0*y1;
            a10 += (double)x1*y0; a11 += (double)x1*y1;
        }
    }
    Xp[(bj+2*ty  )*N + bi+2*tx  ] = (float)a00;
    Xp[(bj+2*ty  )*N + bi+2*tx+1] = (float)a01;
    Xp[(bj+2*ty+1)*N + bi+2*tx  ] = (float)a10;
    Xp[(bj+2*ty+1)*N + bi+2*tx+1] = (float)a11;
}

// ---------------- R = B - A * X0  (A f64, X0 f32 -> R f32, f64 accum) ------------
__global__ void k_gemm_r(const double* __restrict__ Aden, const float* __restrict__ X0,
                         const double* __restrict__ Bmat, float* __restrict__ Rm){
    int s = blockIdx.z;
    const double* Ap = Aden + s*N*N;
    const float* Xp = X0 + s*N*N;
    const double* Bp = Bmat + s*N*N;
    float* Rp = Rm + s*N*N;
    __shared__ double As[32][33];
    __shared__ float Xs[32][33];
    int tx = threadIdx.x, ty = threadIdx.y;
    int tid = ty*16 + tx;
    int bj = blockIdx.y*32, bi = blockIdx.x*32;
    double a00=0, a01=0, a10=0, a11=0;
    for (int kc = 0; kc < N; kc += 32){
        __syncthreads();
        #pragma unroll
        for (int l = 0; l < 4; l++){
            int e = tid + l*256; int r = e >> 5, c = e & 31;
            As[r][c] = Ap[(bj+r)*N + kc + c];
            Xs[r][c] = Xp[(kc+r)*N + bi + c];
        }
        __syncthreads();
        #pragma unroll
        for (int k = 0; k < 32; k++){
            double x0 = As[2*ty][k], x1 = As[2*ty+1][k];
            double y0 = (double)Xs[k][2*tx], y1 = (double)Xs[k][2*tx+1];
            a00 += x0*y0; a01 += x0*y1;
            a10 += x1*y0; a11 += x1*y1;
        }
    }
    int r0 = bj+2*ty, c0 = bi+2*tx;
    Rp[(r0  )*N + c0  ] = (float)(Bp[(r0  )*N + c0  ] - a00);
    Rp[(r0  )*N + c0+1] = (float)(Bp[(r0  )*N + c0+1] - a01);
    Rp[(r0+1)*N + c0  ] = (float)(Bp[(r0+1)*N + c0  ] - a10);
    Rp[(r0+1)*N + c0+1] = (float)(Bp[(r0+1)*N + c0+1] - a11);
}

// ---- X = X0 + G*R looped over sigma; relu(avg) col sums -> dsum.
// ---- Extra grid row (blockIdx.y==8, blockIdx.x<4): numerator solves -> rnum.
__global__ void k_gemm_xl(const float* __restrict__ Gden, const float* __restrict__ Rm,
                          const float* __restrict__ X0, double* __restrict__ dsum,
                          const float* __restrict__ Gnum, const double* __restrict__ Anum,
                          const double* __restrict__ bnum, float* __restrict__ rnum){
    __shared__ float Gs[32][33], Rs[32][33];
    __shared__ double cp[16][33];
    __shared__ double y0[256], rr2[256], bsh[256];
    int tx = threadIdx.x, ty = threadIdx.y;
    int tid = ty*16 + tx;
    if (blockIdx.y == 8){
        if (blockIdx.x >= 4) return;
        int s = blockIdx.x, j = tid;
        const float* Gp = Gnum + s*N*N;
        const double* Ap = Anum + s*N*N;
        const double* bp = bnum + s*N;
        bsh[j] = bp[j];
        __syncthreads();
        double acc = 0;
        for (int k = 0; k < N; k++) acc += (double)Gp[j*N+k] * bsh[k];
        y0[j] = acc;
        __syncthreads();
        acc = 0;
        for (int k = 0; k < N; k++) acc += Ap[j*N+k] * y0[k];
        rr2[j] = bsh[j] - acc;
        __syncthreads();
        acc = 0;
        for (int k = 0; k < N; k++) acc += (double)Gp[j*N+k] * rr2[k];
        rnum[s*N+j] = (float)(y0[j] + acc);
        return;
    }
    int bj = blockIdx.y*32, bi = blockIdx.x*32;
    int r0 = bj+2*ty, c0 = bi+2*tx;
    double s00=0, s01=0, s10=0, s11=0;
    for (int s = 0; s < 4; s++){
        const float* Gp = Gden + s*N*N;
        const float* Rp = Rm + s*N*N;
        const float* X0p = X0 + s*N*N;
        double a00=0, a01=0, a10=0, a11=0;
        for (int kc = 0; kc < N; kc += 32){
            __syncthreads();
            #pragma unroll
            for (int l = 0; l < 4; l++){
                int e = tid + l*256; int r = e >> 5, c = e & 31;
                Gs[r][c] = Gp[(bj+r)*N + kc + c];
                Rs[r][c] = Rp[(kc+r)*N + bi + c];
            }
            __syncthreads();
            #pragma unroll
            for (int k = 0; k < 32; k++){
                float x0 = Gs[2*ty][k], x1 = Gs[2*ty+1][k];
                float y0v = Rs[k][2*tx], y1v = Rs[k][2*tx+1];
                a00 += (double)x0*y0v; a01 += (double)x0*y1v;
                a10 += (double)x1*y0v; a11 += (double)x1*y1v;
            }
        }
        s00 += (double)X0p[(r0  )*N + c0  ] + a00;
        s01 += (double)X0p[(r0  )*N + c0+1] + a01;
        s10 += (double)X0p[(r0+1)*N + c0  ] + a10;
        s11 += (double)X0p[(r0+1)*N + c0+1] + a11;
    }
    double v00 = (double)fmaxf((float)(0.25*s00), 0.f);
    double v01 = (double)fmaxf((float)(0.25*s01), 0.f);
    double v10 = (double)fmaxf((float)(0.25*s10), 0.f);
    double v11 = (double)fmaxf((float)(0.25*s11), 0.f);
    __syncthreads();
    cp[ty][2*tx]   = v00 + v10;
    cp[ty][2*tx+1] = v01 + v11;
    __syncthreads();
    if (tid < 32){
        double ssum = 0;
        #pragma unroll
        for (int t = 0; t < 16; t++) ssum += cp[t][tid];
        atomicAdd(&dsum[bi + tid], ssum);
    }
}

// ---------------- final loss ----------------
__global__ void k_loss2(const double* __restrict__ dsum, const float* __restrict__ rnum,
                        float* __restrict__ out){
    __shared__ double red[256];
    int i = threadIdx.x;
    double denum = dsum[i] + (double)N * 1.0e-3;
    float ravg = 0.25f*(rnum[0*N+i] + rnum[1*N+i] + rnum[2*N+i] + rnum[3*N+i]);
    double rn = (double)fmaxf(ravg, 0.f) + 1.0e-3;
    red[i] = log(rn) + log(denum);
    __syncthreads();
    for (int st = 128; st > 0; st >>= 1){
        if (i < st) red[i] += red[i + st];
        __syncthreads();
    }
    if (i == 0) out[0] = (float)red[0];
}

extern "C" void kernel_launch(void* const* d_in, const int* in_sizes, int n_in,
                              void* d_out, int out_size, void* d_ws, size_t ws_size,
                              hipStream_t stream) {
    (void)in_sizes; (void)n_in; (void)out_size; (void)ws_size;
    const float* z1 = (const float*)d_in[0];
    const float* z2 = (const float*)d_in[1];
    const int*   p1 = (const int*)d_in[2];
    const int*   p2 = (const int*)d_in[3];
    float* out = (float*)d_out;

    char* w = (char*)d_ws;
    size_t o = 0;
    auto carve = [&](size_t bytes) -> char* {
        char* p = w + o;
        o += (bytes + 255) & ~(size_t)255;
        return p;
    };
    // zero-init region first (one memset covers bnum+dsum)
    double*   bnum = (double*) carve((size_t)4*N*sizeof(double));
    double*   dsum = (double*) carve((size_t)N*sizeof(double));
    size_t zbytes = o;
    double* Aden = (double*)carve((size_t)4*N*N*sizeof(double));
    double* Anum = (double*)carve((size_t)4*N*N*sizeof(double));
    float*  M4   = (float*) carve((size_t)4*N*N*sizeof(float));
    float*  U4   = (float*) carve((size_t)4*N*N*sizeof(float));
    double* Bmat = (double*)carve((size_t)4*N*N*sizeof(double));
    float*  Gden = (float*) carve((size_t)4*N*N*sizeof(float));
    float*  Gnum = (float*) carve((size_t)4*N*N*sizeof(float));
    float*  X0   = (float*) carve((size_t)4*N*N*sizeof(float));
    float*  Rm   = (float*) carve((size_t)4*N*N*sizeof(float));
    float*  rnum = (float*) carve((size_t)4*N*sizeof(float));
    double* Smat = (double*)carve((size_t)8*N*N*sizeof(double));
    double* Eg   = (double*)carve((size_t)8*224*32*sizeof(double));
    double* Pg   = (double*)carve((size_t)8*32*32*sizeof(double));

    hipMemsetAsync(d_ws, 0, zbytes, stream);
    k_dist<<<dim3(16,16,5), dim3(16,16), 0, stream>>>(z1, z2, p1, p2,
                                                      Aden, Anum, Smat, M4, U4, bnum);
    k_gemm_nt<<<dim3(8,8,4), dim3(16,16), 0, stream>>>(M4, U4, Bmat);
    for (int k = 0; k < 8; k++){
        k_pivot<<<dim3(8), dim3(1024), 0, stream>>>(Smat, Eg, Pg, k);
        k_step<<<dim3(56,8), dim3(256), 0, stream>>>(Smat, Eg, Pg, k);
    }
    k_gout<<<dim3(2048), dim3(256), 0, stream>>>(Smat, Gden, Gnum);
    k_gemm_x0<<<dim3(8,8,4), dim3(16,16), 0, stream>>>(Gden, Bmat, X0);
    k_gemm_r<<<dim3(8,8,4), dim3(16,16), 0, stream>>>(Aden, X0, Bmat, Rm);
    k_gemm_xl<<<dim3(8,9), dim3(16,16), 0, stream>>>(Gden, Rm, X0, dsum,
                                                     Gnum, Anum, bnum, rnum);
    k_loss2<<<dim3(1), dim3(256), 0, stream>>>(dsum, rnum, out);
}

// Round 10
// 495.114 us; speedup vs baseline: 1.7133x; 1.0666x over previous
//
#include <hip/hip_runtime.h>
#include <math.h>

#define N 256
#define Dd 128

__device__ __forceinline__ double inv2s2_of(int s){
    return (s==0)?0.5:(s==1)?5.0e-3:(s==2)?5.0e-5:5.0e-7;
}

// verified elementwise f64 GJ sweep of a 32x32 LDS tile (rounds 1/4/6).
// After the loop the swept tile = -D^{-1}; we negate so P = D^{-1}.
// Executed by threads tid<64 (r=tid&31, cg=tid>>5), wave-lockstep.
__device__ __forceinline__ void sweep32(double P[32][33], int tid){
    if (tid < 64){
        int r = tid & 31, cg = tid >> 5;
        for (int j = 0; j < 32; j++){
            double d    = P[j][j];
            double invd = 1.0 / d;
            double cr   = P[r][j];
            double s    = cr * invd;
            bool rj = (r == j);
            double nv[16];
            #pragma unroll
            for (int c = 0; c < 16; c++){
                int col = cg*16 + c;
                double pj = P[j][col];
                double v  = P[r][col];
                nv[c] = rj ? ((col == j) ? -invd : v * invd)
                           : ((col == j) ? s : v - s*pj);
            }
            #pragma unroll
            for (int c = 0; c < 16; c++) P[r][cg*16+c] = nv[c];
        }
        #pragma unroll
        for (int c = 0; c < 16; c++) P[r][cg*16+c] = -P[r][cg*16+c];
    }
}

// ------- fused gather + distances + kernel matrices + bnum ------------------
// w=0: (z1,z1)+(z2,z2)         -> Anum(f64,+lam) + S0[4..8)
// w=1: (z1,z1[p1])+(z2,z2[p2]) -> bnum[s][row] += exp
// w=2: (z2[p2],z2[p2])         -> Aden(f64,+lam) + S0[0..4)
// w=3: (z2[p2],z2)             -> M4 (f32)
// w=4: (z1,z2)                 -> U4 (f32)
__global__ void k_dist(const float* __restrict__ z1, const float* __restrict__ z2,
                       const int* __restrict__ p1, const int* __restrict__ p2,
                       double* __restrict__ Aden, double* __restrict__ Anum,
                       double* __restrict__ S0, float* __restrict__ M4,
                       float* __restrict__ U4, double* __restrict__ bnum){
    __shared__ float Xs[16][17], Ys[16][17];
    int w = blockIdx.z;
    int tx = threadIdx.x, ty = threadIdx.y;
    int row = blockIdx.y*16 + ty, col = blockIdx.x*16 + tx;
    const float *Xb[2], *Yb[2]; const int *Xp[2], *Yp[2]; int npair = 1;
    Xb[1]=0; Yb[1]=0; Xp[0]=0; Yp[0]=0; Xp[1]=0; Yp[1]=0;
    switch(w){
        case 0: Xb[0]=z1; Yb[0]=z1; Xb[1]=z2; Yb[1]=z2; npair=2; break;
        case 1: Xb[0]=z1; Yb[0]=z1; Yp[0]=p1; Xb[1]=z2; Yb[1]=z2; Yp[1]=p2; npair=2; break;
        case 2: Xb[0]=z2; Yb[0]=z2; Xp[0]=p2; Yp[0]=p2; break;
        case 3: Xb[0]=z2; Yb[0]=z2; Xp[0]=p2; break;
        default:Xb[0]=z1; Yb[0]=z2; break;
    }
    double acc = 0.0;
    for (int p = 0; p < npair; p++){
        const float* X = Xb[p]; const float* Y = Yb[p];
        int xr = blockIdx.y*16 + ty; if (Xp[p]) xr = Xp[p][xr];
        int yr = blockIdx.x*16 + ty; if (Yp[p]) yr = Yp[p][yr];
        for (int c = 0; c < Dd; c += 16){
            __syncthreads();
            Xs[ty][tx] = X[xr*Dd + c + tx];
            Ys[ty][tx] = Y[yr*Dd + c + tx];
            __syncthreads();
            #pragma unroll
            for (int t = 0; t < 16; t++){
                float d = Xs[ty][t] - Ys[tx][t];
                acc += (double)d * (double)d;
            }
        }
    }
    int o = row*N + col;
    if (w == 0){
        #pragma unroll
        for (int s = 0; s < 4; s++){
            double v = exp(-inv2s2_of(s)*acc);
            if (row == col) v += 1.0e-3;
            Anum[s*N*N + o] = v;
            S0[(4+s)*N*N + o] = v;
        }
    } else if (w == 1){
        #pragma unroll
        for (int s = 0; s < 4; s++){
            double v = exp(-inv2s2_of(s)*acc);
            v += __shfl_down(v, 8, 16);
            v += __shfl_down(v, 4, 16);
            v += __shfl_down(v, 2, 16);
            v += __shfl_down(v, 1, 16);
            if (tx == 0) atomicAdd(&bnum[s*N + row], v);
        }
    } else if (w == 2){
        #pragma unroll
        for (int s = 0; s < 4; s++){
            double v = exp(-inv2s2_of(s)*acc);
            if (row == col) v += 1.0e-3;
            Aden[s*N*N + o] = v;
            S0[s*N*N + o] = v;
        }
    } else if (w == 3){
        #pragma unroll
        for (int s = 0; s < 4; s++) M4[s*N*N + o] = (float)exp(-inv2s2_of(s)*acc);
    } else {
        #pragma unroll
        for (int s = 0; s < 4; s++) U4[s*N*N + o] = (float)exp(-inv2s2_of(s)*acc);
    }
}

// ====== blocked f64 GJ inversion: ping-pong multi-launch (round-6 algebra) ======
// Step k reads src entirely, writes dst entirely (all 64 tiles covered:
// 49 trailing + 7 col + 7 row + 1 pivot). No E snapshot needed (src stable).
// Next pivot sweep is folded into the trailing block producing dst(k+1,k+1);
// Pg double-buffered by parity to avoid same-launch read/write race.

__global__ void k_pivot0(const double* __restrict__ S0, double* __restrict__ Pg0){
    __shared__ double P[32][33];
    int mat = blockIdx.x;
    const double* S = S0 + (size_t)mat*65536;
    double* Pp = Pg0 + (size_t)mat*1024;
    int tid = threadIdx.x;
    #pragma unroll
    for (int l = 0; l < 4; l++){
        int e = tid + l*256; P[e>>5][e&31] = S[(size_t)(e>>5)*N + (e&31)];
    }
    __syncthreads();
    sweep32(P, tid);
    __syncthreads();
    #pragma unroll
    for (int l = 0; l < 4; l++){
        int e = tid + l*256; Pp[e] = P[e>>5][e&31];
    }
}

// grid (56, 8): bx<49 trailing (I,J); bx>=49 colrow T. 256 threads.
__global__ void k_step(const double* __restrict__ Ssrc, double* __restrict__ Sdst,
                       const double* __restrict__ PgS, double* __restrict__ PgD, int k){
    __shared__ double Pl[32][33], EJ[32][33], Cl[32][33], El[32][33];
    int bx = blockIdx.x, mat = blockIdx.y;
    const double* S = Ssrc + (size_t)mat*65536;
    double* D = Sdst + (size_t)mat*65536;
    const double* Pp = PgS + (size_t)mat*1024;
    int tid = threadIdx.x;
    int Kb = k*32;
    #pragma unroll
    for (int l = 0; l < 4; l++){
        int e = tid + l*256; Pl[e>>5][e&31] = Pp[e];
    }
    if (bx < 49){
        int I = bx / 7, J = bx % 7;
        int GI = ((I < k) ? I : I + 1) * 32;
        int GJ = ((J < k) ? J : J + 1) * 32;
        #pragma unroll
        for (int l = 0; l < 4; l++){
            int e = tid + l*256; int r = e >> 5, c = e & 31;
            El[r][c] = S[(size_t)(GI + r)*N + Kb + c];
            EJ[r][c] = S[(size_t)(GJ + r)*N + Kb + c];
        }
        __syncthreads();
        #pragma unroll
        for (int l = 0; l < 4; l++){
            int e = tid + l*256; int r = e >> 5, c = e & 31;
            double acc = 0.0;
            #pragma unroll
            for (int kk = 0; kk < 32; kk++) acc += EJ[r][kk] * Pl[kk][c];
            Cl[r][c] = acc;
        }
        __syncthreads();
        int pr = tid >> 4, pc = tid & 15;
        int r0 = 2*pr, c0 = 2*pc;
        double a00 = S[(size_t)(GI+r0)*N + GJ+c0];
        double a01 = S[(size_t)(GI+r0)*N + GJ+c0+1];
        double a10 = S[(size_t)(GI+r0+1)*N + GJ+c0];
        double a11 = S[(size_t)(GI+r0+1)*N + GJ+c0+1];
        #pragma unroll
        for (int kk = 0; kk < 32; kk++){
            double e0 = El[r0][kk],   e1 = El[r0+1][kk];
            double b0 = Cl[c0][kk],   b1 = Cl[c0+1][kk];
            a00 -= e0*b0; a01 -= e0*b1;
            a10 -= e1*b0; a11 -= e1*b1;
        }
        double* Dp = D + (size_t)(GI + r0)*N + GJ + c0;
        Dp[0]   = a00; Dp[1]   = a01;
        Dp[N]   = a10; Dp[N+1] = a11;
        // fold next pivot sweep: this block produced dst tile (k+1,k+1)
        if (I == k && J == k && k < 7){
            __syncthreads();
            El[r0][c0]   = a00; El[r0][c0+1]   = a01;
            El[r0+1][c0] = a10; El[r0+1][c0+1] = a11;
            __syncthreads();
            sweep32(El, tid);
            __syncthreads();
            double* Pd = PgD + (size_t)mat*1024;
            #pragma unroll
            for (int l = 0; l < 4; l++){
                int e = tid + l*256; Pd[e] = El[e>>5][e&31];
            }
        }
    } else {
        int T = bx - 49;
        int GT = ((T < k) ? T : T + 1) * 32;
        #pragma unroll
        for (int l = 0; l < 4; l++){
            int e = tid + l*256; int r = e >> 5, c = e & 31;
            El[r][c] = S[(size_t)(GT + r)*N + Kb + c];
        }
        __syncthreads();
        #pragma unroll
        for (int l = 0; l < 4; l++){
            int e = tid + l*256; int r = e >> 5, c = e & 31;
            double acc = 0.0;
            #pragma unroll
            for (int kk = 0; kk < 32; kk++) acc += El[r][kk] * Pl[kk][c];
            Cl[r][c] = acc;
        }
        __syncthreads();
        #pragma unroll
        for (int l = 0; l < 4; l++){
            int e = tid + l*256; int r = e >> 5, c = e & 31;
            D[(size_t)(GT + r)*N + Kb + c] = Cl[r][c];          // col block
        }
        #pragma unroll
        for (int l = 0; l < 4; l++){
            int e = tid + l*256; int cc = e >> 5, rr = e & 31;
            D[(size_t)(Kb + cc)*N + GT + rr] = Cl[rr][cc];      // row block = C^T
        }
        if (T == 0){
            #pragma unroll
            for (int l = 0; l < 4; l++){
                int e = tid + l*256; int i = e >> 5, j = e & 31;
                D[(size_t)(Kb + i)*N + Kb + j] = -Pl[i][j];     // pivot block
            }
        }
    }
}

// ---------------- B = M * U^T (f32 in, f64 accum/out), batched over sigma --------
__global__ void k_gemm_nt(const float* __restrict__ M4, const float* __restrict__ U4,
                          double* __restrict__ Bmat){
    int s = blockIdx.z;
    const float* Mp = M4 + s*N*N;
    const float* Up = U4 + s*N*N;
    double* Bp = Bmat + s*N*N;
    __shared__ float Ms[32][33], Us[32][33];
    int tx = threadIdx.x, ty = threadIdx.y;
    int tid = ty*16 + tx;
    int bj = blockIdx.y*32, bi = blockIdx.x*32;
    double a00=0, a01=0, a10=0, a11=0;
    for (int kc = 0; kc < N; kc += 32){
        __syncthreads();
        #pragma unroll
        for (int l = 0; l < 4; l++){
            int e = tid + l*256; int r = e >> 5, c = e & 31;
            Ms[r][c] = Mp[(bj+r)*N + kc + c];
            Us[r][c] = Up[(bi+r)*N + kc + c];
        }
        __syncthreads();
        #pragma unroll
        for (int k = 0; k < 32; k++){
            float x0 = Ms[2*ty][k], x1 = Ms[2*ty+1][k];
            float y0 = Us[2*tx][k], y1 = Us[2*tx+1][k];
            a00 += (double)x0*y0; a01 += (double)x0*y1;
            a10 += (double)x1*y0; a11 += (double)x1*y1;
        }
    }
    Bp[(bj+2*ty  )*N + bi+2*tx  ] = a00;
    Bp[(bj+2*ty  )*N + bi+2*tx+1] = a01;
    Bp[(bj+2*ty+1)*N + bi+2*tx  ] = a10;
    Bp[(bj+2*ty+1)*N + bi+2*tx+1] = a11;
}

// ------ X0 = G * B, G = -(float)Sfin (f64 sweep result), f64 accum ------
__global__ void k_gemm_x0(const double* __restrict__ Sfin, const double* __restrict__ Bmat,
                          float* __restrict__ X0){
    int s = blockIdx.z;
    const double* Sp = Sfin + (size_t)s*N*N;
    const double* Bp = Bmat + s*N*N;
    float* Xp = X0 + s*N*N;
    __shared__ float Gs[32][33];
    __shared__ double Bs[32][33];
    int tx = threadIdx.x, ty = threadIdx.y;
    int tid = ty*16 + tx;
    int bj = blockIdx.y*32, bi = blockIdx.x*32;
    double a00=0, a01=0, a10=0, a11=0;
    for (int kc = 0; kc < N; kc += 32){
        __syncthreads();
        #pragma unroll
        for (int l = 0; l < 4; l++){
            int e = tid + l*256; int r = e >> 5, c = e & 31;
            Gs[r][c] = -(float)Sp[(size_t)(bj+r)*N + kc + c];
            Bs[r][c] = Bp[(kc+r)*N + bi + c];
        }
        __syncthreads();
        #pragma unroll
        for (int k = 0; k < 32; k++){
            float x0 = Gs[2*ty][k], x1 = Gs[2*ty+1][k];
            double y0 = Bs[k][2*tx], y1 = Bs[k][2*tx+1];
            a00 += (double)x0*y0; a01 += (double)x0*y1;
            a10 += (double)x1*y0; a11 += (double)x1*y1;
        }
    }
    Xp[(bj+2*ty  )*N + bi+2*tx  ] = (float)a00;
    Xp[(bj+2*ty  )*N + bi+2*tx+1] = (float)a01;
    Xp[(bj+2*ty+1)*N + bi+2*tx  ] = (float)a10;
    Xp[(bj+2*ty+1)*N + bi+2*tx+1] = (float)a11;
}

// ---------------- R = B - A * X0  (A f64, X0 f32 -> R f32, f64 accum) ------------
__global__ void k_gemm_r(const double* __restrict__ Aden, const float* __restrict__ X0,
                         const double* __restrict__ Bmat, float* __restrict__ Rm){
    int s = blockIdx.z;
    const double* Ap = Aden + s*N*N;
    const float* Xp = X0 + s*N*N;
    const double* Bp = Bmat + s*N*N;
    float* Rp = Rm + s*N*N;
    __shared__ double As[32][33];
    __shared__ float Xs[32][33];
    int tx = threadIdx.x, ty = threadIdx.y;
    int tid = ty*16 + tx;
    int bj = blockIdx.y*32, bi = blockIdx.x*32;
    double a00=0, a01=0, a10=0, a11=0;
    for (int kc = 0; kc < N; kc += 32){
        __syncthreads();
        #pragma unroll
        for (int l = 0; l < 4; l++){
            int e = tid + l*256; int r = e >> 5, c = e & 31;
            As[r][c] = Ap[(bj+r)*N + kc + c];
            Xs[r][c] = Xp[(kc+r)*N + bi + c];
        }
        __syncthreads();
        #pragma unroll
        for (int k = 0; k < 32; k++){
            double x0 = As[2*ty][k], x1 = As[2*ty+1][k];
            double y0 = (double)Xs[k][2*tx], y1 = (double)Xs[k][2*tx+1];
            a00 += x0*y0; a01 += x0*y1;
            a10 += x1*y0; a11 += x1*y1;
        }
    }
    int r0 = bj+2*ty, c0 = bi+2*tx;
    Rp[(r0  )*N + c0  ] = (float)(Bp[(r0  )*N + c0  ] - a00);
    Rp[(r0  )*N + c0+1] = (float)(Bp[(r0  )*N + c0+1] - a01);
    Rp[(r0+1)*N + c0  ] = (float)(Bp[(r0+1)*N + c0  ] - a10);
    Rp[(r0+1)*N + c0+1] = (float)(Bp[(r0+1)*N + c0+1] - a11);
}

// ---- X = X0 + G*R looped over sigma; relu(avg) col sums -> dsum.
// ---- Extra grid row (blockIdx.y==8, blockIdx.x<4): numerator solves -> rnum,
//      with G/A accessed COLUMN-wise ([k*N+j]) via symmetry => coalesced.
__global__ void k_gemm_xl(const double* __restrict__ Sfin, const float* __restrict__ Rm,
                          const float* __restrict__ X0, double* __restrict__ dsum,
                          const double* __restrict__ Anum,
                          const double* __restrict__ bnum, float* __restrict__ rnum){
    __shared__ float Gs[32][33], Rs[32][33];
    __shared__ double cp[16][33];
    __shared__ double y0[256], rr2[256], bsh[256];
    int tx = threadIdx.x, ty = threadIdx.y;
    int tid = ty*16 + tx;
    if (blockIdx.y == 8){
        if (blockIdx.x >= 4) return;
        int s = blockIdx.x, j = tid;
        const double* Sn = Sfin + (size_t)(4+s)*N*N;   // Gnum = -Sn (symmetric)
        const double* Ap = Anum + s*N*N;               // symmetric
        const double* bp = bnum + s*N;
        bsh[j] = bp[j];
        __syncthreads();
        double acc = 0;
        for (int k = 0; k < N; k++) acc -= Sn[(size_t)k*N+j] * bsh[k];
        y0[j] = acc;
        __syncthreads();
        acc = 0;
        for (int k = 0; k < N; k++) acc += Ap[(size_t)k*N+j] * y0[k];
        rr2[j] = bsh[j] - acc;
        __syncthreads();
        acc = 0;
        for (int k = 0; k < N; k++) acc -= Sn[(size_t)k*N+j] * rr2[k];
        rnum[s*N+j] = (float)(y0[j] + acc);
        return;
    }
    int bj = blockIdx.y*32, bi = blockIdx.x*32;
    int r0 = bj+2*ty, c0 = bi+2*tx;
    double s00=0, s01=0, s10=0, s11=0;
    for (int s = 0; s < 4; s++){
        const double* Sp = Sfin + (size_t)s*N*N;
        const float* Rp = Rm + s*N*N;
        const float* X0p = X0 + s*N*N;
        double a00=0, a01=0, a10=0, a11=0;
        for (int kc = 0; kc < N; kc += 32){
            __syncthreads();
            #pragma unroll
            for (int l = 0; l < 4; l++){
                int e = tid + l*256; int r = e >> 5, c = e & 31;
                Gs[r][c] = -(float)Sp[(size_t)(bj+r)*N + kc + c];
                Rs[r][c] = Rp[(kc+r)*N + bi + c];
            }
            __syncthreads();
            #pragma unroll
            for (int k = 0; k < 32; k++){
                float x0 = Gs[2*ty][k], x1 = Gs[2*ty+1][k];
                float y0v = Rs[k][2*tx], y1v = Rs[k][2*tx+1];
                a00 += (double)x0*y0v; a01 += (double)x0*y1v;
                a10 += (double)x1*y0v; a11 += (double)x1*y1v;
            }
        }
        s00 += (double)X0p[(r0  )*N + c0  ] + a00;
        s01 += (double)X0p[(r0  )*N + c0+1] + a01;
        s10 += (double)X0p[(r0+1)*N + c0  ] + a10;
        s11 += (double)X0p[(r0+1)*N + c0+1] + a11;
    }
    double v00 = (double)fmaxf((float)(0.25*s00), 0.f);
    double v01 = (double)fmaxf((float)(0.25*s01), 0.f);
    double v10 = (double)fmaxf((float)(0.25*s10), 0.f);
    double v11 = (double)fmaxf((float)(0.25*s11), 0.f);
    __syncthreads();
    cp[ty][2*tx]   = v00 + v10;
    cp[ty][2*tx+1] = v01 + v11;
    __syncthreads();
    if (tid < 32){
        double ssum = 0;
        #pragma unroll
        for (int t = 0; t < 16; t++) ssum += cp[t][tid];
        atomicAdd(&dsum[bi + tid], ssum);
    }
}

// ---------------- final loss ----------------
__global__ void k_loss2(const double* __restrict__ dsum, const float* __restrict__ rnum,
                        float* __restrict__ out){
    __shared__ double red[256];
    int i = threadIdx.x;
    double denum = dsum[i] + (double)N * 1.0e-3;
    float ravg = 0.25f*(rnum[0*N+i] + rnum[1*N+i] + rnum[2*N+i] + rnum[3*N+i]);
    double rn = (double)fmaxf(ravg, 0.f) + 1.0e-3;
    red[i] = log(rn) + log(denum);
    __syncthreads();
    for (int st = 128; st > 0; st >>= 1){
        if (i < st) red[i] += red[i + st];
        __syncthreads();
    }
    if (i == 0) out[0] = (float)red[0];
}

extern "C" void kernel_launch(void* const* d_in, const int* in_sizes, int n_in,
                              void* d_out, int out_size, void* d_ws, size_t ws_size,
                              hipStream_t stream) {
    (void)in_sizes; (void)n_in; (void)out_size; (void)ws_size;
    const float* z1 = (const float*)d_in[0];
    const float* z2 = (const float*)d_in[1];
    const int*   p1 = (const int*)d_in[2];
    const int*   p2 = (const int*)d_in[3];
    float* out = (float*)d_out;

    char* w = (char*)d_ws;
    size_t o = 0;
    auto carve = [&](size_t bytes) -> char* {
        char* p = w + o;
        o += (bytes + 255) & ~(size_t)255;
        return p;
    };
    // zero-init region first (one memset covers bnum+dsum)
    double*   bnum = (double*) carve((size_t)4*N*sizeof(double));
    double*   dsum = (double*) carve((size_t)N*sizeof(double));
    size_t zbytes = o;
    double* Aden = (double*)carve((size_t)4*N*N*sizeof(double));
    double* Anum = (double*)carve((size_t)4*N*N*sizeof(double));
    float*  M4   = (float*) carve((size_t)4*N*N*sizeof(float));
    float*  U4   = (float*) carve((size_t)4*N*N*sizeof(float));
    double* Bmat = (double*)carve((size_t)4*N*N*sizeof(double));
    float*  X0   = (float*) carve((size_t)4*N*N*sizeof(float));
    float*  Rm   = (float*) carve((size_t)4*N*N*sizeof(float));
    float*  rnum = (float*) carve((size_t)4*N*sizeof(float));
    double* S0   = (double*)carve((size_t)8*N*N*sizeof(double));  // ping
    double* S1   = (double*)carve((size_t)8*N*N*sizeof(double));  // pong
    double* Pg0  = (double*)carve((size_t)8*32*32*sizeof(double));
    double* Pg1  = (double*)carve((size_t)8*32*32*sizeof(double));

    hipMemsetAsync(d_ws, 0, zbytes, stream);
    k_dist<<<dim3(16,16,5), dim3(16,16), 0, stream>>>(z1, z2, p1, p2,
                                                      Aden, Anum, S0, M4, U4, bnum);
    k_gemm_nt<<<dim3(8,8,4), dim3(16,16), 0, stream>>>(M4, U4, Bmat);
    k_pivot0<<<dim3(8), dim3(256), 0, stream>>>(S0, Pg0);
    for (int k = 0; k < 8; k++){
        double* src = (k & 1) ? S1 : S0;
        double* dst = (k & 1) ? S0 : S1;
        double* ps  = (k & 1) ? Pg1 : Pg0;
        double* pd  = (k & 1) ? Pg0 : Pg1;
        k_step<<<dim3(56,8), dim3(256), 0, stream>>>(src, dst, ps, pd, k);
    }
    // after k=7 (odd): final swept matrices in S0
    k_gemm_x0<<<dim3(8,8,4), dim3(16,16), 0, stream>>>(S0, Bmat, X0);
    k_gemm_r<<<dim3(8,8,4), dim3(16,16), 0, stream>>>(Aden, X0, Bmat, Rm);
    k_gemm_xl<<<dim3(8,9), dim3(16,16), 0, stream>>>(S0, Rm, X0, dsum,
                                                     Anum, bnum, rnum);
    k_loss2<<<dim3(1), dim3(256), 0, stream>>>(dsum, rnum, out);
}

// Round 11
// 439.275 us; speedup vs baseline: 1.9311x; 1.1271x over previous
//
#include <hip/hip_runtime.h>
#include <math.h>

#define N 256
#define Dd 128

__device__ __forceinline__ double inv2s2_of(int s){
    return (s==0)?0.5:(s==1)?5.0e-3:(s==2)?5.0e-5:5.0e-7;
}

// verified elementwise f64 GJ sweep of a 32x32 LDS tile (rounds 1/4/6/10).
// After the loop the swept tile = -D^{-1}; negate so P = D^{-1}.
__device__ __forceinline__ void sweep32(double P[32][33], int tid){
    if (tid < 64){
        int r = tid & 31, cg = tid >> 5;
        for (int j = 0; j < 32; j++){
            double d    = P[j][j];
            double invd = 1.0 / d;
            double cr   = P[r][j];
            double s    = cr * invd;
            bool rj = (r == j);
            double nv[16];
            #pragma unroll
            for (int c = 0; c < 16; c++){
                int col = cg*16 + c;
                double pj = P[j][col];
                double v  = P[r][col];
                nv[c] = rj ? ((col == j) ? -invd : v * invd)
                           : ((col == j) ? s : v - s*pj);
            }
            #pragma unroll
            for (int c = 0; c < 16; c++) P[r][cg*16+c] = nv[c];
        }
        #pragma unroll
        for (int c = 0; c < 16; c++) P[r][cg*16+c] = -P[r][cg*16+c];
    }
}

// ------- fused gather + distances + kernel matrices + bnum partials ---------
// w=0: (z1,z1)+(z2,z2)         -> S0[4..8) (Anum, f64, +lam)
// w=1: (z1,z1[p1])+(z2,z2[p2]) -> bpart[s][row][bx] (16-col partial sums)
// w=2: (z2[p2],z2[p2])         -> S0[0..4) (Aden, f64, +lam)
// w=3: (z2[p2],z2)             -> M4 (f32)
// w=4: (z1,z2)                 -> U4 (f32)
__global__ void k_dist(const float* __restrict__ z1, const float* __restrict__ z2,
                       const int* __restrict__ p1, const int* __restrict__ p2,
                       double* __restrict__ S0, float* __restrict__ M4,
                       float* __restrict__ U4, double* __restrict__ bpart){
    __shared__ float Xs[16][17], Ys[16][17];
    int w = blockIdx.z;
    int tx = threadIdx.x, ty = threadIdx.y;
    int row = blockIdx.y*16 + ty, col = blockIdx.x*16 + tx;
    const float *Xb[2], *Yb[2]; const int *Xp[2], *Yp[2]; int npair = 1;
    Xb[1]=0; Yb[1]=0; Xp[0]=0; Yp[0]=0; Xp[1]=0; Yp[1]=0;
    switch(w){
        case 0: Xb[0]=z1; Yb[0]=z1; Xb[1]=z2; Yb[1]=z2; npair=2; break;
        case 1: Xb[0]=z1; Yb[0]=z1; Yp[0]=p1; Xb[1]=z2; Yb[1]=z2; Yp[1]=p2; npair=2; break;
        case 2: Xb[0]=z2; Yb[0]=z2; Xp[0]=p2; Yp[0]=p2; break;
        case 3: Xb[0]=z2; Yb[0]=z2; Xp[0]=p2; break;
        default:Xb[0]=z1; Yb[0]=z2; break;
    }
    double acc = 0.0;
    for (int p = 0; p < npair; p++){
        const float* X = Xb[p]; const float* Y = Yb[p];
        int xr = blockIdx.y*16 + ty; if (Xp[p]) xr = Xp[p][xr];
        int yr = blockIdx.x*16 + ty; if (Yp[p]) yr = Yp[p][yr];
        for (int c = 0; c < Dd; c += 16){
            __syncthreads();
            Xs[ty][tx] = X[xr*Dd + c + tx];
            Ys[ty][tx] = Y[yr*Dd + c + tx];
            __syncthreads();
            #pragma unroll
            for (int t = 0; t < 16; t++){
                float d = Xs[ty][t] - Ys[tx][t];
                acc += (double)d * (double)d;
            }
        }
    }
    int o = row*N + col;
    if (w == 0){
        #pragma unroll
        for (int s = 0; s < 4; s++){
            double v = exp(-inv2s2_of(s)*acc);
            if (row == col) v += 1.0e-3;
            S0[(size_t)(4+s)*N*N + o] = v;
        }
    } else if (w == 1){
        #pragma unroll
        for (int s = 0; s < 4; s++){
            double v = exp(-inv2s2_of(s)*acc);
            v += __shfl_down(v, 8, 16);
            v += __shfl_down(v, 4, 16);
            v += __shfl_down(v, 2, 16);
            v += __shfl_down(v, 1, 16);
            if (tx == 0) bpart[((size_t)s*N + row)*16 + blockIdx.x] = v;
        }
    } else if (w == 2){
        #pragma unroll
        for (int s = 0; s < 4; s++){
            double v = exp(-inv2s2_of(s)*acc);
            if (row == col) v += 1.0e-3;
            S0[(size_t)s*N*N + o] = v;
        }
    } else if (w == 3){
        #pragma unroll
        for (int s = 0; s < 4; s++) M4[s*N*N + o] = (float)exp(-inv2s2_of(s)*acc);
    } else {
        #pragma unroll
        for (int s = 0; s < 4; s++) U4[s*N*N + o] = (float)exp(-inv2s2_of(s)*acc);
    }
}

// ------ B = M*U^T (f32 in, f64 out); z=4 slice: pivot0 sweep + dsum zero ------
__global__ void k_gemm_nt(const float* __restrict__ M4, const float* __restrict__ U4,
                          double* __restrict__ Bmat, const double* __restrict__ S0,
                          double* __restrict__ Pg0, double* __restrict__ dsum){
    __shared__ float Ms[32][33], Us[32][33];
    __shared__ double P[32][33];
    int tx = threadIdx.x, ty = threadIdx.y;
    int tid = ty*16 + tx;
    if (blockIdx.z == 4){
        if (blockIdx.y != 0) return;
        int mat = blockIdx.x;
        if (mat == 0) dsum[tid] = 0.0;
        const double* S = S0 + (size_t)mat*65536;
        #pragma unroll
        for (int l = 0; l < 4; l++){
            int e = tid + l*256; P[e>>5][e&31] = S[(size_t)(e>>5)*N + (e&31)];
        }
        __syncthreads();
        sweep32(P, tid);
        __syncthreads();
        double* Pp = Pg0 + (size_t)mat*1024;
        #pragma unroll
        for (int l = 0; l < 4; l++){
            int e = tid + l*256; Pp[e] = P[e>>5][e&31];
        }
        return;
    }
    int s = blockIdx.z;
    const float* Mp = M4 + s*N*N;
    const float* Up = U4 + s*N*N;
    double* Bp = Bmat + s*N*N;
    int bj = blockIdx.y*32, bi = blockIdx.x*32;
    double a00=0, a01=0, a10=0, a11=0;
    for (int kc = 0; kc < N; kc += 32){
        __syncthreads();
        #pragma unroll
        for (int l = 0; l < 4; l++){
            int e = tid + l*256; int r = e >> 5, c = e & 31;
            Ms[r][c] = Mp[(bj+r)*N + kc + c];
            Us[r][c] = Up[(bi+r)*N + kc + c];
        }
        __syncthreads();
        #pragma unroll
        for (int k = 0; k < 32; k++){
            float x0 = Ms[2*ty][k], x1 = Ms[2*ty+1][k];
            float y0 = Us[2*tx][k], y1 = Us[2*tx+1][k];
            a00 += (double)x0*y0; a01 += (double)x0*y1;
            a10 += (double)x1*y0; a11 += (double)x1*y1;
        }
    }
    Bp[(bj+2*ty  )*N + bi+2*tx  ] = a00;
    Bp[(bj+2*ty  )*N + bi+2*tx+1] = a01;
    Bp[(bj+2*ty+1)*N + bi+2*tx  ] = a10;
    Bp[(bj+2*ty+1)*N + bi+2*tx+1] = a11;
}

// ====== blocked f64 GJ inversion: ping-pong multi-launch (round-10-verified) =====
// grid (56, 8): bx<49 trailing (I,J); bx>=49 colrow T. 256 threads.
__global__ void k_step(const double* __restrict__ Ssrc, double* __restrict__ Sdst,
                       const double* __restrict__ PgS, double* __restrict__ PgD, int k){
    __shared__ double Pl[32][33], EJ[32][33], Cl[32][33], El[32][33];
    int bx = blockIdx.x, mat = blockIdx.y;
    const double* S = Ssrc + (size_t)mat*65536;
    double* D = Sdst + (size_t)mat*65536;
    const double* Pp = PgS + (size_t)mat*1024;
    int tid = threadIdx.x;
    int Kb = k*32;
    #pragma unroll
    for (int l = 0; l < 4; l++){
        int e = tid + l*256; Pl[e>>5][e&31] = Pp[e];
    }
    if (bx < 49){
        int I = bx / 7, J = bx % 7;
        int GI = ((I < k) ? I : I + 1) * 32;
        int GJ = ((J < k) ? J : J + 1) * 32;
        #pragma unroll
        for (int l = 0; l < 4; l++){
            int e = tid + l*256; int r = e >> 5, c = e & 31;
            El[r][c] = S[(size_t)(GI + r)*N + Kb + c];
            EJ[r][c] = S[(size_t)(GJ + r)*N + Kb + c];
        }
        __syncthreads();
        #pragma unroll
        for (int l = 0; l < 4; l++){
            int e = tid + l*256; int r = e >> 5, c = e & 31;
            double acc = 0.0;
            #pragma unroll
            for (int kk = 0; kk < 32; kk++) acc += EJ[r][kk] * Pl[kk][c];
            Cl[r][c] = acc;
        }
        __syncthreads();
        int pr = tid >> 4, pc = tid & 15;
        int r0 = 2*pr, c0 = 2*pc;
        double a00 = S[(size_t)(GI+r0)*N + GJ+c0];
        double a01 = S[(size_t)(GI+r0)*N + GJ+c0+1];
        double a10 = S[(size_t)(GI+r0+1)*N + GJ+c0];
        double a11 = S[(size_t)(GI+r0+1)*N + GJ+c0+1];
        #pragma unroll
        for (int kk = 0; kk < 32; kk++){
            double e0 = El[r0][kk],   e1 = El[r0+1][kk];
            double b0 = Cl[c0][kk],   b1 = Cl[c0+1][kk];
            a00 -= e0*b0; a01 -= e0*b1;
            a10 -= e1*b0; a11 -= e1*b1;
        }
        double* Dp = D + (size_t)(GI + r0)*N + GJ + c0;
        Dp[0]   = a00; Dp[1]   = a01;
        Dp[N]   = a10; Dp[N+1] = a11;
        // fold next pivot sweep: this block produced dst tile (k+1,k+1)
        if (I == k && J == k && k < 7){
            __syncthreads();
            El[r0][c0]   = a00; El[r0][c0+1]   = a01;
            El[r0+1][c0] = a10; El[r0+1][c0+1] = a11;
            __syncthreads();
            sweep32(El, tid);
            __syncthreads();
            double* Pd = PgD + (size_t)mat*1024;
            #pragma unroll
            for (int l = 0; l < 4; l++){
                int e = tid + l*256; Pd[e] = El[e>>5][e&31];
            }
        }
    } else {
        int T = bx - 49;
        int GT = ((T < k) ? T : T + 1) * 32;
        #pragma unroll
        for (int l = 0; l < 4; l++){
            int e = tid + l*256; int r = e >> 5, c = e & 31;
            El[r][c] = S[(size_t)(GT + r)*N + Kb + c];
        }
        __syncthreads();
        #pragma unroll
        for (int l = 0; l < 4; l++){
            int e = tid + l*256; int r = e >> 5, c = e & 31;
            double acc = 0.0;
            #pragma unroll
            for (int kk = 0; kk < 32; kk++) acc += El[r][kk] * Pl[kk][c];
            Cl[r][c] = acc;
        }
        __syncthreads();
        #pragma unroll
        for (int l = 0; l < 4; l++){
            int e = tid + l*256; int r = e >> 5, c = e & 31;
            D[(size_t)(GT + r)*N + Kb + c] = Cl[r][c];          // col block
        }
        #pragma unroll
        for (int l = 0; l < 4; l++){
            int e = tid + l*256; int cc = e >> 5, rr = e & 31;
            D[(size_t)(Kb + cc)*N + GT + rr] = Cl[rr][cc];      // row block = C^T
        }
        if (T == 0){
            #pragma unroll
            for (int l = 0; l < 4; l++){
                int e = tid + l*256; int i = e >> 5, j = e & 31;
                D[(size_t)(Kb + i)*N + Kb + j] = -Pl[i][j];     // pivot block
            }
        }
    }
}

// ------ X[s] = G[s]*B[s] in f64 (G = -Sfin, no IR needed: err ~ cond*eps64) ------
__global__ void k_x(const double* __restrict__ Sfin, const double* __restrict__ Bmat,
                    float* __restrict__ Xm){
    int s = blockIdx.z;
    const double* Sp = Sfin + (size_t)s*N*N;
    const double* Bp = Bmat + (size_t)s*N*N;
    float* Xp = Xm + (size_t)s*N*N;
    __shared__ double Gs[32][33], Bs[32][33];
    int tx = threadIdx.x, ty = threadIdx.y;
    int tid = ty*16 + tx;
    int bj = blockIdx.y*32, bi = blockIdx.x*32;
    double a00=0, a01=0, a10=0, a11=0;
    for (int kc = 0; kc < N; kc += 32){
        __syncthreads();
        #pragma unroll
        for (int l = 0; l < 4; l++){
            int e = tid + l*256; int r = e >> 5, c = e & 31;
            Gs[r][c] = -Sp[(size_t)(bj+r)*N + kc + c];
            Bs[r][c] = Bp[(size_t)(kc+r)*N + bi + c];
        }
        __syncthreads();
        #pragma unroll
        for (int k = 0; k < 32; k++){
            double x0 = Gs[2*ty][k], x1 = Gs[2*ty+1][k];
            double y0 = Bs[k][2*tx], y1 = Bs[k][2*tx+1];
            a00 += x0*y0; a01 += x0*y1;
            a10 += x1*y0; a11 += x1*y1;
        }
    }
    Xp[(bj+2*ty  )*N + bi+2*tx  ] = (float)a00;
    Xp[(bj+2*ty  )*N + bi+2*tx+1] = (float)a01;
    Xp[(bj+2*ty+1)*N + bi+2*tx  ] = (float)a10;
    Xp[(bj+2*ty+1)*N + bi+2*tx+1] = (float)a11;
}

// ---- b<64: relu(avg over sigma of Xm) column sums -> dsum (f64 atomics).
// ---- b in 64..67: numerator solve rnum[s] = Gnum*b (coalesced via symmetry).
__global__ void k_red(const float* __restrict__ Xm, const double* __restrict__ Sfin,
                      const double* __restrict__ bpart, double* __restrict__ dsum,
                      float* __restrict__ rnum){
    __shared__ double cp[32][33];
    __shared__ double bsh[256];
    int b = blockIdx.x, tid = threadIdx.x;
    if (b < 64){
        int bj = (b >> 3)*32, bi = (b & 7)*32;
        #pragma unroll
        for (int l = 0; l < 4; l++){
            int e = tid + l*256; int r = e >> 5, c = e & 31;
            int o = (bj + r)*N + bi + c;
            float x = Xm[0*N*N + o] + Xm[1*N*N + o] + Xm[2*N*N + o] + Xm[3*N*N + o];
            cp[r][c] = (double)fmaxf(0.25f*x, 0.f);
        }
        __syncthreads();
        if (tid < 32){
            double ssum = 0;
            #pragma unroll
            for (int r = 0; r < 32; r++) ssum += cp[r][tid];
            atomicAdd(&dsum[bi + tid], ssum);
        }
    } else {
        int s = b - 64, j = tid;
        const double* Sn = Sfin + (size_t)(4+s)*N*N;   // Gnum = -Sn (symmetric)
        const double* bp = bpart + (size_t)s*N*16;
        double acc = 0;
        #pragma unroll
        for (int t = 0; t < 16; t++) acc += bp[j*16 + t];
        bsh[j] = acc;
        __syncthreads();
        double y = 0;
        for (int k = 0; k < N; k++) y -= Sn[(size_t)k*N + j] * bsh[k];
        rnum[s*N + j] = (float)y;
    }
}

// ---------------- final loss ----------------
__global__ void k_loss2(const double* __restrict__ dsum, const float* __restrict__ rnum,
                        float* __restrict__ out){
    __shared__ double red[256];
    int i = threadIdx.x;
    double denum = dsum[i] + (double)N * 1.0e-3;
    float ravg = 0.25f*(rnum[0*N+i] + rnum[1*N+i] + rnum[2*N+i] + rnum[3*N+i]);
    double rn = (double)fmaxf(ravg, 0.f) + 1.0e-3;
    red[i] = log(rn) + log(denum);
    __syncthreads();
    for (int st = 128; st > 0; st >>= 1){
        if (i < st) red[i] += red[i + st];
        __syncthreads();
    }
    if (i == 0) out[0] = (float)red[0];
}

extern "C" void kernel_launch(void* const* d_in, const int* in_sizes, int n_in,
                              void* d_out, int out_size, void* d_ws, size_t ws_size,
                              hipStream_t stream) {
    (void)in_sizes; (void)n_in; (void)out_size; (void)ws_size;
    const float* z1 = (const float*)d_in[0];
    const float* z2 = (const float*)d_in[1];
    const int*   p1 = (const int*)d_in[2];
    const int*   p2 = (const int*)d_in[3];
    float* out = (float*)d_out;

    char* w = (char*)d_ws;
    size_t o = 0;
    auto carve = [&](size_t bytes) -> char* {
        char* p = w + o;
        o += (bytes + 255) & ~(size_t)255;
        return p;
    };
    double* bpart = (double*)carve((size_t)4*N*16*sizeof(double));
    double* dsum  = (double*)carve((size_t)N*sizeof(double));
    float*  M4    = (float*) carve((size_t)4*N*N*sizeof(float));
    float*  U4    = (float*) carve((size_t)4*N*N*sizeof(float));
    double* Bmat  = (double*)carve((size_t)4*N*N*sizeof(double));
    float*  Xm    = (float*) carve((size_t)4*N*N*sizeof(float));
    float*  rnum  = (float*) carve((size_t)4*N*sizeof(float));
    double* S0    = (double*)carve((size_t)8*N*N*sizeof(double));  // ping
    double* S1    = (double*)carve((size_t)8*N*N*sizeof(double));  // pong
    double* Pg0   = (double*)carve((size_t)8*32*32*sizeof(double));
    double* Pg1   = (double*)carve((size_t)8*32*32*sizeof(double));

    k_dist<<<dim3(16,16,5), dim3(16,16), 0, stream>>>(z1, z2, p1, p2,
                                                      S0, M4, U4, bpart);
    k_gemm_nt<<<dim3(8,8,5), dim3(16,16), 0, stream>>>(M4, U4, Bmat, S0, Pg0, dsum);
    for (int k = 0; k < 8; k++){
        double* src = (k & 1) ? S1 : S0;
        double* dst = (k & 1) ? S0 : S1;
        double* ps  = (k & 1) ? Pg1 : Pg0;
        double* pd  = (k & 1) ? Pg0 : Pg1;
        k_step<<<dim3(56,8), dim3(256), 0, stream>>>(src, dst, ps, pd, k);
    }
    // after k=7 (odd): final swept matrices in S0
    k_x<<<dim3(8,8,4), dim3(16,16), 0, stream>>>(S0, Bmat, Xm);
    k_red<<<dim3(68), dim3(256), 0, stream>>>(Xm, S0, bpart, dsum, rnum);
    k_loss2<<<dim3(1), dim3(256), 0, stream>>>(dsum, rnum, out);
}